// Round 7
// baseline (19980.316 us; speedup 1.0000x reference)
//
#include <hip/hip_runtime.h>
#include <hip/hip_bf16.h>
#include <math.h>

#define BB 16
#define TT 12
#define NN 1024
#define FF 8
#define HH 64
#define EE 32768
#define DIN 320   // H * (2K+1)
#define ODIM 96   // F * HORIZON
#define PRE 192   // preA row stride: [r|u|c] x 64

// ---------------- edge_index dtype normalization (int64 vs int32) ----------------
// Proven int32 in round 6 (flag=0 path); kept as cheap insurance.
__global__ void k_ei_detect(const int* __restrict__ ei_raw, int* __restrict__ flag) {
    __shared__ int s[256];
    s[threadIdx.x] = ei_raw[2 * threadIdx.x + 1];
    __syncthreads();
    for (int st = 128; st > 0; st >>= 1) {
        if (threadIdx.x < st) s[threadIdx.x] |= s[threadIdx.x + st];
        __syncthreads();
    }
    if (threadIdx.x == 0) flag[0] = (s[0] == 0) ? 1 : 0;   // 1 => int64
}

__global__ void k_ei_norm(const int* __restrict__ ei_raw, const int* __restrict__ flag,
                          int* __restrict__ ei32) {
    int j = blockIdx.x * 256 + threadIdx.x;   // [0, 2E)
    ei32[j] = flag[0] ? ei_raw[2 * j] : ei_raw[j];   // int64: take low word (LE)
}

// ---------------- support normalization: rinv = 1/rowsum, cinv = 1/colsum ----------------
__global__ void k_rowsum(const float* __restrict__ adj, float* __restrict__ rinv) {
    __shared__ float s[256];
    int i = blockIdx.x;
    float acc = 0.f;
    for (int j = threadIdx.x; j < NN; j += 256) acc += adj[i * NN + j];
    s[threadIdx.x] = acc;
    __syncthreads();
    for (int st = 128; st > 0; st >>= 1) {
        if (threadIdx.x < st) s[threadIdx.x] += s[threadIdx.x + st];
        __syncthreads();
    }
    if (threadIdx.x == 0) rinv[i] = (s[0] != 0.f) ? 1.f / s[0] : 0.f;
}

__global__ void k_colsum(const float* __restrict__ adj, float* __restrict__ cinv) {
    int j = blockIdx.x * 256 + threadIdx.x;
    float acc = 0.f;
    for (int i = 0; i < NN; i++) acc += adj[i * NN + j];
    cinv[j] = (acc != 0.f) ? 1.f / acc : 0.f;
}

// ---------------- encoder: xtE[b,n,:] = x[b,t,n,:] @ W_enc + b_enc + emb[n,:] ----------------
__global__ void k_enc(const float* __restrict__ x, const float* __restrict__ W_enc,
                      const float* __restrict__ b_enc, const float* __restrict__ emb,
                      float* __restrict__ xtE, int t) {
    size_t idx = (size_t)blockIdx.x * 256 + threadIdx.x;   // B*N*H
    size_t row = idx >> 6; int ch = (int)(idx & 63);
    int b = (int)(row >> 10), n = (int)(row & 1023);
    const float* xr = x + (((size_t)b * TT + t) * NN + n) * FF;
    float acc = b_enc[ch] + emb[(size_t)n * HH + ch];
    #pragma unroll
    for (int f = 0; f < FF; f++) acc += xr[f] * W_enc[f * HH + ch];
    xtE[idx] = acc;
}

// ---------------- fused hop GEMM + gate-preactivation accumulate ----------------
// Yhop[b,w,:] = sum_v A[w,v] * Xin[b,v,:]   (A = normalized adj, fwd or bwd)
// pre[b,w, g*64+q] (+)= sum_ch Yhop[b,w,ch] * Wg[(wrow+ch)*64 + q]
//   mode 0: groups r,u,c   mode 1: r,u   mode 2: c only
// grid (NN/64, 1, BB); each block owns (node-tile, batch) exclusively -> non-atomic RMW.
__global__ __launch_bounds__(256) void k_hopacc(
        const float* __restrict__ adj, const float* __restrict__ ninv, int bwd,
        const float* __restrict__ Xin, float* __restrict__ Yhop, int writeY,
        float* __restrict__ pre,
        const float* __restrict__ Wr, const float* __restrict__ Wu, const float* __restrict__ Wc,
        int wrow, int mode, int init,
        const float* __restrict__ br, const float* __restrict__ bu, const float* __restrict__ bc) {
    int b = blockIdx.z;
    int w0 = blockIdx.x * 64;
    const float* X = Xin + (size_t)b * NN * HH;

    __shared__ float As[16][68];
    __shared__ float Bs[16][68];
    __shared__ float S[64][65];

    int tid = threadIdx.x;
    int ar = tid >> 2,  ak  = (tid & 3) * 4;    // fwd A-tile map: 64 rows x 16 k
    int bk = tid >> 4,  bc4 = (tid & 15) * 4;   // X-tile (and bwd A-tile) map: 16 k x 64 cols
    int ty = tid >> 4,  tx  = tid & 15;

    float acc[4][4] = {};

    for (int k0 = 0; k0 < NN; k0 += 16) {
        if (!bwd) {
            // A_fwd[w,v] = adj[w,v] * rinv[w]
            float4 av = *(const float4*)(adj + (size_t)(w0 + ar) * NN + k0 + ak);
            float rv = ninv[w0 + ar];
            As[ak + 0][ar] = av.x * rv; As[ak + 1][ar] = av.y * rv;
            As[ak + 2][ar] = av.z * rv; As[ak + 3][ar] = av.w * rv;
        } else {
            // A_bwd[w,v] = adj[v,w] * cinv[w]
            float4 av = *(const float4*)(adj + (size_t)(k0 + bk) * NN + w0 + bc4);
            As[bk][bc4 + 0] = av.x * ninv[w0 + bc4 + 0];
            As[bk][bc4 + 1] = av.y * ninv[w0 + bc4 + 1];
            As[bk][bc4 + 2] = av.z * ninv[w0 + bc4 + 2];
            As[bk][bc4 + 3] = av.w * ninv[w0 + bc4 + 3];
        }
        float4 xv = *(const float4*)(X + (size_t)(k0 + bk) * HH + bc4);
        *(float4*)&Bs[bk][bc4] = xv;
        __syncthreads();
        #pragma unroll
        for (int kk = 0; kk < 16; kk++) {
            const float4 a4 = *(const float4*)&As[kk][ty * 4];
            const float4 b4 = *(const float4*)&Bs[kk][tx * 4];
            acc[0][0] += a4.x * b4.x; acc[0][1] += a4.x * b4.y; acc[0][2] += a4.x * b4.z; acc[0][3] += a4.x * b4.w;
            acc[1][0] += a4.y * b4.x; acc[1][1] += a4.y * b4.y; acc[1][2] += a4.y * b4.z; acc[1][3] += a4.y * b4.w;
            acc[2][0] += a4.z * b4.x; acc[2][1] += a4.z * b4.y; acc[2][2] += a4.z * b4.z; acc[2][3] += a4.z * b4.w;
            acc[3][0] += a4.w * b4.x; acc[3][1] += a4.w * b4.y; acc[3][2] += a4.w * b4.z; acc[3][3] += a4.w * b4.w;
        }
        __syncthreads();
    }

    // stage tile to LDS (and optionally write hop output for chaining)
    float* Y = Yhop + (size_t)b * NN * HH;
    #pragma unroll
    for (int i = 0; i < 4; i++) {
        if (writeY) {
            float4 o = make_float4(acc[i][0], acc[i][1], acc[i][2], acc[i][3]);
            *(float4*)(Y + (size_t)(w0 + ty * 4 + i) * HH + tx * 4) = o;
        }
        S[ty * 4 + i][tx * 4 + 0] = acc[i][0];
        S[ty * 4 + i][tx * 4 + 1] = acc[i][1];
        S[ty * 4 + i][tx * 4 + 2] = acc[i][2];
        S[ty * 4 + i][tx * 4 + 3] = acc[i][3];
    }
    __syncthreads();

    int ng = (mode == 0) ? 3 : ((mode == 1) ? 2 : 1);
    int gb = (mode == 2) ? 2 : 0;
    int tot = 64 * 64 * ng;
    for (int idx = tid; idx < tot; idx += 256) {
        int n = idx / (64 * ng);
        int rem = idx - n * (64 * ng);
        int g = gb + (rem >> 6);
        int q = rem & 63;
        const float* W = (g == 0) ? Wr : ((g == 1) ? Wu : Wc);
        float s = 0.f;
        #pragma unroll 8
        for (int ch = 0; ch < 64; ch++) s += S[n][ch] * W[(wrow + ch) * HH + q];
        float* dp = pre + ((size_t)b * NN + w0 + n) * PRE + g * 64 + q;
        float v = init ? ((g == 0) ? br[q] : ((g == 1) ? bu[q] : bc[q])) : *dp;
        *dp = v + s;
    }
}

// ---------------- r = sigmoid(preA[:,0:64]); rh = r * h ----------------
__global__ void k_fin_r(const float* __restrict__ pre, const float* __restrict__ h,
                        float* __restrict__ rh) {
    size_t idx = (size_t)blockIdx.x * 256 + threadIdx.x;   // B*N*H
    size_t row = idx >> 6; int q = (int)(idx & 63);
    float r = 1.f / (1.f + expf(-pre[row * PRE + q]));
    rh[idx] = r * h[idx];
}

// ---------------- h = u*h + (1-u)*tanh(preC) ----------------
__global__ void k_hupd(const float* __restrict__ pre, float* __restrict__ h) {
    size_t idx = (size_t)blockIdx.x * 256 + threadIdx.x;   // B*N*H
    size_t row = idx >> 6; int q = (int)(idx & 63);
    float u = 1.f / (1.f + expf(-pre[row * PRE + 64 + q]));
    float c = tanhf(pre[row * PRE + 128 + q]);
    h[idx] = u * h[idx] + (1.f - u) * c;
}

// ---------------- DiffConv (sparse) ----------------
__global__ void k_deg(const int* __restrict__ ei32, const float* __restrict__ ew,
                      float* __restrict__ degd, float* __restrict__ degs) {
    int e = blockIdx.x * 256 + threadIdx.x;
    float w = ew[e];
    atomicAdd(&degd[ei32[EE + e]], w);  // by dst
    atomicAdd(&degs[ei32[e]], w);       // by src
}

__global__ void k_wnorm(const int* __restrict__ ei32, const float* __restrict__ ew,
                        const float* __restrict__ degd, const float* __restrict__ degs,
                        float* __restrict__ wf, float* __restrict__ wb) {
    int e = blockIdx.x * 256 + threadIdx.x;
    float w = ew[e];
    float dd = degd[ei32[EE + e]];
    float ds = degs[ei32[e]];
    wf[e] = dd > 0.f ? w / dd : 0.f;
    wb[e] = ds > 0.f ? w / ds : 0.f;
}

__global__ void k_featd_init(const float* __restrict__ h, float* __restrict__ featd) {
    size_t idx = (size_t)blockIdx.x * 256 + threadIdx.x;   // B*N*DIN
    size_t row = idx / DIN; int c = (int)(idx % DIN);
    featd[idx] = (c < HH) ? h[row * HH + c] : 0.f;
}

__global__ void k_scatter(float* featd, const int* __restrict__ sidx,
                          const int* __restrict__ didx, const float* __restrict__ w,
                          int in_off, int out_off) {
    size_t idx = (size_t)blockIdx.x * 256 + threadIdx.x;   // E * H
    int e = (int)(idx >> 6), c = (int)(idx & 63);
    int s = sidx[e], d = didx[e];
    float wv = w[e];
    const float* src = featd + (size_t)s * DIN + in_off + c;
    float* dst = featd + (size_t)d * DIN + out_off + c;
    for (int b = 0; b < BB; b++)
        atomicAdd(dst + (size_t)b * NN * DIN, src[(size_t)b * NN * DIN] * wv);
}

__global__ __launch_bounds__(256) void k_z(
        const float* __restrict__ featd, const float* __restrict__ W_diff,
        const float* __restrict__ b_diff, float* __restrict__ z) {
    int row0 = blockIdx.x * 4;
    __shared__ float sF[4 * DIN];
    int tid = threadIdx.x;
    for (int i = tid; i < 4 * DIN / 4; i += 256)
        *(float4*)&sF[i * 4] = *(const float4*)&featd[(size_t)row0 * DIN + (size_t)i * 4];
    __syncthreads();
    int lr = tid >> 6, ch = tid & 63;
    const float* f = &sF[lr * DIN];
    float acc = b_diff[ch];
    for (int k = 0; k < DIN; k++) acc += f[k] * W_diff[k * HH + ch];
    z[(size_t)(row0 + lr) * HH + ch] = acc;
}

// out[b,t,n,f] = (z @ W_dec + b_dec)[b,n,t*F+f]   -- OUTPUT IS FLOAT32
__global__ void k_dec(const float* __restrict__ z, const float* __restrict__ W_dec,
                      const float* __restrict__ b_dec, float* __restrict__ out) {
    size_t idx = (size_t)blockIdx.x * 256 + threadIdx.x;   // B*N*ODIM
    size_t row = idx / ODIM; int o = (int)(idx % ODIM);
    const float* zr = z + row * HH;
    float acc = b_dec[o];
    for (int k = 0; k < HH; k++) acc += zr[k] * W_dec[k * ODIM + o];
    int b = (int)(row >> 10), n = (int)(row & 1023);
    int t = o >> 3, f = o & 7;
    out[(((size_t)b * TT + t) * NN + n) * FF + f] = acc;
}

extern "C" void kernel_launch(void* const* d_in, const int* in_sizes, int n_in,
                              void* d_out, int out_size, void* d_ws, size_t ws_size,
                              hipStream_t stream) {
    // Established: float inputs are f32; edge_index int32; OUTPUT f32 (reference dtype).
    const float* x      = (const float*)d_in[0];
    const int*   eiraw  = (const int*)  d_in[1];
    const float* ew     = (const float*)d_in[2];
    const float* adj    = (const float*)d_in[3];
    const float* W_enc  = (const float*)d_in[4];
    const float* b_enc  = (const float*)d_in[5];
    const float* emb    = (const float*)d_in[6];
    const float* W_r    = (const float*)d_in[7];
    const float* b_r    = (const float*)d_in[8];
    const float* W_u    = (const float*)d_in[9];
    const float* b_u    = (const float*)d_in[10];
    const float* W_c    = (const float*)d_in[11];
    const float* b_c    = (const float*)d_in[12];
    const float* W_diff = (const float*)d_in[13];
    const float* b_diff = (const float*)d_in[14];
    const float* W_dec  = (const float*)d_in[15];
    const float* b_dec  = (const float*)d_in[16];

    // ---- workspace: ~24.8 MiB total ----
    float* ws   = (float*)d_ws;
    float* rinv = ws;                                   // 1024
    float* cinv = rinv + NN;                            // 1024
    float* degd = cinv + NN;                            // 1024
    float* degs = degd + NN;                            // 1024
    float* wf   = degs + NN;                            // E
    float* wb   = wf + EE;                              // E
    int*   eifl = (int*)(wb + EE);                      // 4 (flag)
    int*   ei32 = eifl + 4;                             // 2E int32
    float* xtE  = (float*)(ei32 + 2 * EE);              // B*N*64   (4 MiB)  also: rh
    float* hopA = xtE + (size_t)BB * NN * HH;           // B*N*64   (4 MiB)
    float* preA = hopA + (size_t)BB * NN * HH;          // B*N*192  (12 MiB)
    float* h    = preA + (size_t)BB * NN * PRE;         // B*N*64   (4 MiB)
    float* featd = xtE;   // alias: B*N*320 (20 MiB) == xtE..preA span, h untouched
    float* z     = h;     // alias: h dead after k_featd_init

    hipMemsetAsync(h, 0, (size_t)BB * NN * HH * 4, stream);
    hipMemsetAsync(degd, 0, (size_t)2 * NN * 4, stream);

    k_ei_detect<<<1, 256, 0, stream>>>(eiraw, eifl);
    k_ei_norm<<<2 * EE / 256, 256, 0, stream>>>(eiraw, eifl, ei32);
    k_rowsum<<<NN, 256, 0, stream>>>(adj, rinv);
    k_colsum<<<NN / 256, 256, 0, stream>>>(adj, cinv);

    dim3 gh(NN / 64, 1, BB);
    const int G = BB * NN * HH / 256;   // 4096
    for (int t = 0; t < TT; t++) {
        k_enc<<<G, 256, 0, stream>>>(x, W_enc, b_enc, emb, xtE, t);
        // x-part hops (shared by gates r,u AND candidate c): mode 0, W rows 0/128/256/384
        k_hopacc<<<gh, 256, 0, stream>>>(adj, rinv, 0, xtE,  hopA, 1, preA, W_r, W_u, W_c,   0, 0, 1, b_r, b_u, b_c);
        k_hopacc<<<gh, 256, 0, stream>>>(adj, rinv, 0, hopA, hopA, 0, preA, W_r, W_u, W_c, 128, 0, 0, b_r, b_u, b_c);
        k_hopacc<<<gh, 256, 0, stream>>>(adj, cinv, 1, xtE,  hopA, 1, preA, W_r, W_u, W_c, 256, 0, 0, b_r, b_u, b_c);
        k_hopacc<<<gh, 256, 0, stream>>>(adj, cinv, 1, hopA, hopA, 0, preA, W_r, W_u, W_c, 384, 0, 0, b_r, b_u, b_c);
        // h-part hops (gates r,u only): mode 1, W rows 64/192/320/448
        k_hopacc<<<gh, 256, 0, stream>>>(adj, rinv, 0, h,    hopA, 1, preA, W_r, W_u, W_c,  64, 1, 0, b_r, b_u, b_c);
        k_hopacc<<<gh, 256, 0, stream>>>(adj, rinv, 0, hopA, hopA, 0, preA, W_r, W_u, W_c, 192, 1, 0, b_r, b_u, b_c);
        k_hopacc<<<gh, 256, 0, stream>>>(adj, cinv, 1, h,    hopA, 1, preA, W_r, W_u, W_c, 320, 1, 0, b_r, b_u, b_c);
        k_hopacc<<<gh, 256, 0, stream>>>(adj, cinv, 1, hopA, hopA, 0, preA, W_r, W_u, W_c, 448, 1, 0, b_r, b_u, b_c);
        // r = sigmoid(preR); rh = r*h  (xtE consumed -> reuse as rh)
        k_fin_r<<<G, 256, 0, stream>>>(preA, h, xtE);
        // rh-part hops (candidate c only): mode 2, Wc rows 64/192/320/448
        k_hopacc<<<gh, 256, 0, stream>>>(adj, rinv, 0, xtE,  hopA, 1, preA, W_r, W_u, W_c,  64, 2, 0, b_r, b_u, b_c);
        k_hopacc<<<gh, 256, 0, stream>>>(adj, rinv, 0, hopA, hopA, 0, preA, W_r, W_u, W_c, 192, 2, 0, b_r, b_u, b_c);
        k_hopacc<<<gh, 256, 0, stream>>>(adj, cinv, 1, xtE,  hopA, 1, preA, W_r, W_u, W_c, 320, 2, 0, b_r, b_u, b_c);
        k_hopacc<<<gh, 256, 0, stream>>>(adj, cinv, 1, hopA, hopA, 0, preA, W_r, W_u, W_c, 448, 2, 0, b_r, b_u, b_c);
        // h = u*h + (1-u)*tanh(preC)
        k_hupd<<<G, 256, 0, stream>>>(preA, h);
    }

    // ---- DiffConv readout ----
    k_deg<<<EE / 256, 256, 0, stream>>>(ei32, ew, degd, degs);
    k_wnorm<<<EE / 256, 256, 0, stream>>>(ei32, ew, degd, degs, wf, wb);
    k_featd_init<<<(BB * NN * DIN) / 256, 256, 0, stream>>>(h, featd);
    const int* srcp = ei32;
    const int* dstp = ei32 + EE;
    k_scatter<<<(EE * HH) / 256, 256, 0, stream>>>(featd, srcp, dstp, wf, 0, HH);
    k_scatter<<<(EE * HH) / 256, 256, 0, stream>>>(featd, srcp, dstp, wf, HH, 2 * HH);
    k_scatter<<<(EE * HH) / 256, 256, 0, stream>>>(featd, dstp, srcp, wb, 0, 3 * HH);
    k_scatter<<<(EE * HH) / 256, 256, 0, stream>>>(featd, dstp, srcp, wb, 3 * HH, 4 * HH);
    k_z<<<BB * NN / 4, 256, 0, stream>>>(featd, W_diff, b_diff, z);
    k_dec<<<(BB * NN * ODIM) / 256, 256, 0, stream>>>(z, W_dec, b_dec, (float*)d_out);
}

// Round 8
// 6334.784 us; speedup vs baseline: 3.1541x; 3.1541x over previous
//
#include <hip/hip_runtime.h>
#include <hip/hip_bf16.h>
#include <math.h>

#define BB 16
#define TT 12
#define NN 1024
#define FF 8
#define HH 64
#define EE 32768
#define DIN 320   // H * (2K+1)
#define ODIM 96   // F * HORIZON
#define FS 512    // feats row stride: [fwd1|fwd2|bwd1|bwd2] x [x|h](128)

// ---------------- edge_index insurance (proven int32; keep pass-through) ----------------
__global__ void k_ei_detect(const int* __restrict__ ei_raw, int* __restrict__ flag) {
    __shared__ int s[256];
    s[threadIdx.x] = ei_raw[2 * threadIdx.x + 1];
    __syncthreads();
    for (int st = 128; st > 0; st >>= 1) {
        if (threadIdx.x < st) s[threadIdx.x] |= s[threadIdx.x + st];
        __syncthreads();
    }
    if (threadIdx.x == 0) flag[0] = (s[0] == 0) ? 1 : 0;
}

__global__ void k_ei_norm(const int* __restrict__ ei_raw, const int* __restrict__ flag,
                          int* __restrict__ ei32) {
    int j = blockIdx.x * 256 + threadIdx.x;
    ei32[j] = flag[0] ? ei_raw[2 * j] : ei_raw[j];
}

// ---------------- support normalization ----------------
__global__ void k_rowsum(const float* __restrict__ adj, float* __restrict__ rinv) {
    __shared__ float s[256];
    int i = blockIdx.x;
    float acc = 0.f;
    for (int j = threadIdx.x; j < NN; j += 256) acc += adj[i * NN + j];
    s[threadIdx.x] = acc;
    __syncthreads();
    for (int st = 128; st > 0; st >>= 1) {
        if (threadIdx.x < st) s[threadIdx.x] += s[threadIdx.x + st];
        __syncthreads();
    }
    if (threadIdx.x == 0) rinv[i] = (s[0] != 0.f) ? 1.f / s[0] : 0.f;
}

__global__ void k_colsum(const float* __restrict__ adj, float* __restrict__ cinv) {
    int j = blockIdx.x * 256 + threadIdx.x;
    float acc = 0.f;
    for (int i = 0; i < NN; i++) acc += adj[i * NN + j];
    cinv[j] = (acc != 0.f) ? 1.f / acc : 0.f;
}

// ---------------- xh build: cols 0-63 = enc(x_t), 64-127 = h ----------------
__global__ void k_enc2(const float* __restrict__ x, const float* __restrict__ W_enc,
                       const float* __restrict__ b_enc, const float* __restrict__ emb,
                       const float* __restrict__ h, float* __restrict__ xh, int t) {
    size_t idx = (size_t)blockIdx.x * 256 + threadIdx.x;   // B*N*128
    size_t row = idx >> 7; int c = (int)(idx & 127);
    if (c < HH) {
        int b = (int)(row >> 10), n = (int)(row & 1023);
        const float* xr = x + (((size_t)b * TT + t) * NN + n) * FF;
        float acc = b_enc[c] + emb[(size_t)n * HH + c];
        #pragma unroll
        for (int f = 0; f < FF; f++) acc += xr[f] * W_enc[f * HH + c];
        xh[idx] = acc;
    } else {
        xh[idx] = h[row * HH + (c - HH)];
    }
}

// ---------------- hop GEMM: feats[b, :, s*256+oco+ct*64 ...] = A_s @ Xin-tile ----------------
// grid (16 rowtiles, nct coltiles, 32 = b*2+s); 4 blocks/CU.
__global__ __launch_bounds__(256) void k_hop(
        const float* __restrict__ adj, const float* __restrict__ rinv, const float* __restrict__ cinv,
        const float* __restrict__ Xin, int in_stride, int iso, int ico,
        float* __restrict__ feats, int oco) {
    int zz = blockIdx.z;
    int b = zz >> 1, s = zz & 1;
    int ct = blockIdx.y;
    int w0 = blockIdx.x * 64;
    const float* ninv = s ? cinv : rinv;
    const float* X = Xin + (size_t)b * NN * in_stride + s * iso + ico + ct * 64;
    float* Y = feats + (size_t)b * NN * FS + s * 256 + oco + ct * 64;

    __shared__ float As[16][68];
    __shared__ float Bs[16][68];

    int tid = threadIdx.x;
    int ar = tid >> 2,  ak  = (tid & 3) * 4;
    int bk = tid >> 4,  bc4 = (tid & 15) * 4;
    int ty = tid >> 4,  tx  = tid & 15;

    float acc[4][4] = {};

    for (int k0 = 0; k0 < NN; k0 += 16) {
        if (!s) {
            float4 av = *(const float4*)(adj + (size_t)(w0 + ar) * NN + k0 + ak);
            float rv = ninv[w0 + ar];
            As[ak + 0][ar] = av.x * rv; As[ak + 1][ar] = av.y * rv;
            As[ak + 2][ar] = av.z * rv; As[ak + 3][ar] = av.w * rv;
        } else {
            float4 av = *(const float4*)(adj + (size_t)(k0 + bk) * NN + w0 + bc4);
            As[bk][bc4 + 0] = av.x * ninv[w0 + bc4 + 0];
            As[bk][bc4 + 1] = av.y * ninv[w0 + bc4 + 1];
            As[bk][bc4 + 2] = av.z * ninv[w0 + bc4 + 2];
            As[bk][bc4 + 3] = av.w * ninv[w0 + bc4 + 3];
        }
        float4 xv = *(const float4*)(X + (size_t)(k0 + bk) * in_stride + bc4);
        *(float4*)&Bs[bk][bc4] = xv;
        __syncthreads();
        #pragma unroll
        for (int kk = 0; kk < 16; kk++) {
            const float4 a4 = *(const float4*)&As[kk][ty * 4];
            const float4 b4 = *(const float4*)&Bs[kk][tx * 4];
            acc[0][0] += a4.x * b4.x; acc[0][1] += a4.x * b4.y; acc[0][2] += a4.x * b4.z; acc[0][3] += a4.x * b4.w;
            acc[1][0] += a4.y * b4.x; acc[1][1] += a4.y * b4.y; acc[1][2] += a4.y * b4.z; acc[1][3] += a4.y * b4.w;
            acc[2][0] += a4.z * b4.x; acc[2][1] += a4.z * b4.y; acc[2][2] += a4.z * b4.z; acc[2][3] += a4.z * b4.w;
            acc[3][0] += a4.w * b4.x; acc[3][1] += a4.w * b4.y; acc[3][2] += a4.w * b4.z; acc[3][3] += a4.w * b4.w;
        }
        __syncthreads();
    }
    #pragma unroll
    for (int i = 0; i < 4; i++) {
        float4 o = make_float4(acc[i][0], acc[i][1], acc[i][2], acc[i][3]);
        *(float4*)(Y + (size_t)(w0 + ty * 4 + i) * FS + tx * 4) = o;
    }
}

// ---------------- gates GEMM: sigmoid(feats @ W_g + b_g); ct=0 -> rh=r*h, ct=1 -> u ----------------
// grid (256 rowtiles over B*N, 2)
__global__ __launch_bounds__(256) void k_gates(
        const float* __restrict__ feats,
        const float* __restrict__ W_r, const float* __restrict__ W_u,
        const float* __restrict__ b_r, const float* __restrict__ b_u,
        const float* __restrict__ h,
        float* __restrict__ rh, float* __restrict__ u_buf) {
    int ct = blockIdx.y;
    int row0 = blockIdx.x * 64;
    const float* W = ct ? W_u : W_r;
    const float* bias = ct ? b_u : b_r;

    __shared__ float Fa[16][68];
    __shared__ float Wb[16][68];

    int tid = threadIdx.x;
    int ar = tid >> 2,  ak  = (tid & 3) * 4;
    int bk = tid >> 4,  bc4 = (tid & 15) * 4;
    int ty = tid >> 4,  tx  = tid & 15;

    float acc[4][4] = {};

    for (int k0 = 0; k0 < FS; k0 += 16) {
        float4 fv = *(const float4*)(feats + (size_t)(row0 + ar) * FS + k0 + ak);
        Fa[ak + 0][ar] = fv.x; Fa[ak + 1][ar] = fv.y;
        Fa[ak + 2][ar] = fv.z; Fa[ak + 3][ar] = fv.w;
        float4 wv = *(const float4*)(W + (size_t)(k0 + bk) * HH + bc4);
        *(float4*)&Wb[bk][bc4] = wv;
        __syncthreads();
        #pragma unroll
        for (int kk = 0; kk < 16; kk++) {
            const float4 a4 = *(const float4*)&Fa[kk][ty * 4];
            const float4 b4 = *(const float4*)&Wb[kk][tx * 4];
            acc[0][0] += a4.x * b4.x; acc[0][1] += a4.x * b4.y; acc[0][2] += a4.x * b4.z; acc[0][3] += a4.x * b4.w;
            acc[1][0] += a4.y * b4.x; acc[1][1] += a4.y * b4.y; acc[1][2] += a4.y * b4.z; acc[1][3] += a4.y * b4.w;
            acc[2][0] += a4.z * b4.x; acc[2][1] += a4.z * b4.y; acc[2][2] += a4.z * b4.z; acc[2][3] += a4.z * b4.w;
            acc[3][0] += a4.w * b4.x; acc[3][1] += a4.w * b4.y; acc[3][2] += a4.w * b4.z; acc[3][3] += a4.w * b4.w;
        }
        __syncthreads();
    }
    #pragma unroll
    for (int i = 0; i < 4; i++) {
        size_t row = row0 + ty * 4 + i;
        #pragma unroll
        for (int j = 0; j < 4; j++) {
            int c = tx * 4 + j;
            float v = 1.f / (1.f + expf(-(acc[i][j] + bias[c])));
            if (ct == 0) rh[row * HH + c] = v * h[row * HH + c];
            else         u_buf[row * HH + c] = v;
        }
    }
}

// ---------------- candidate GEMM + h update: h = u*h + (1-u)*tanh(feats@W_c + b_c) ----------------
// grid (512 rowtiles of 32 over B*N)
__global__ __launch_bounds__(256) void k_cand(
        const float* __restrict__ feats, const float* __restrict__ W_c,
        const float* __restrict__ b_c, const float* __restrict__ u_buf,
        float* __restrict__ h) {
    int row0 = blockIdx.x * 32;

    __shared__ float Fa[16][36];
    __shared__ float Wb[16][68];

    int tid = threadIdx.x;
    int ar = tid >> 3,  ak2 = (tid & 7) * 2;
    int bk = tid >> 4,  bc4 = (tid & 15) * 4;
    int ty = tid >> 4,  tx  = tid & 15;

    float acc[2][4] = {};

    for (int k0 = 0; k0 < FS; k0 += 16) {
        float2 fv = *(const float2*)(feats + (size_t)(row0 + ar) * FS + k0 + ak2);
        Fa[ak2 + 0][ar] = fv.x; Fa[ak2 + 1][ar] = fv.y;
        float4 wv = *(const float4*)(W_c + (size_t)(k0 + bk) * HH + bc4);
        *(float4*)&Wb[bk][bc4] = wv;
        __syncthreads();
        #pragma unroll
        for (int kk = 0; kk < 16; kk++) {
            float a0 = Fa[kk][ty * 2 + 0];
            float a1 = Fa[kk][ty * 2 + 1];
            const float4 b4 = *(const float4*)&Wb[kk][tx * 4];
            acc[0][0] += a0 * b4.x; acc[0][1] += a0 * b4.y; acc[0][2] += a0 * b4.z; acc[0][3] += a0 * b4.w;
            acc[1][0] += a1 * b4.x; acc[1][1] += a1 * b4.y; acc[1][2] += a1 * b4.z; acc[1][3] += a1 * b4.w;
        }
        __syncthreads();
    }
    #pragma unroll
    for (int i = 0; i < 2; i++) {
        size_t row = row0 + ty * 2 + i;
        #pragma unroll
        for (int j = 0; j < 4; j++) {
            int c = tx * 4 + j;
            float cv = tanhf(acc[i][j] + b_c[c]);
            float u = u_buf[row * HH + c];
            float hv = h[row * HH + c];
            h[row * HH + c] = u * hv + (1.f - u) * cv;
        }
    }
}

// ---------------- DiffConv (sparse) ----------------
__global__ void k_deg(const int* __restrict__ ei32, const float* __restrict__ ew,
                      float* __restrict__ degd, float* __restrict__ degs) {
    int e = blockIdx.x * 256 + threadIdx.x;
    float w = ew[e];
    atomicAdd(&degd[ei32[EE + e]], w);
    atomicAdd(&degs[ei32[e]], w);
}

__global__ void k_wnorm(const int* __restrict__ ei32, const float* __restrict__ ew,
                        const float* __restrict__ degd, const float* __restrict__ degs,
                        float* __restrict__ wf, float* __restrict__ wb) {
    int e = blockIdx.x * 256 + threadIdx.x;
    float w = ew[e];
    float dd = degd[ei32[EE + e]];
    float ds = degs[ei32[e]];
    wf[e] = dd > 0.f ? w / dd : 0.f;
    wb[e] = ds > 0.f ? w / ds : 0.f;
}

__global__ void k_featd_init(const float* __restrict__ h, float* __restrict__ featd) {
    size_t idx = (size_t)blockIdx.x * 256 + threadIdx.x;
    size_t row = idx / DIN; int c = (int)(idx % DIN);
    featd[idx] = (c < HH) ? h[row * HH + c] : 0.f;
}

__global__ void k_scatter(float* featd, const int* __restrict__ sidx,
                          const int* __restrict__ didx, const float* __restrict__ w,
                          int in_off, int out_off) {
    size_t idx = (size_t)blockIdx.x * 256 + threadIdx.x;
    int e = (int)(idx >> 6), c = (int)(idx & 63);
    int s = sidx[e], d = didx[e];
    float wv = w[e];
    const float* src = featd + (size_t)s * DIN + in_off + c;
    float* dst = featd + (size_t)d * DIN + out_off + c;
    for (int b = 0; b < BB; b++)
        atomicAdd(dst + (size_t)b * NN * DIN, src[(size_t)b * NN * DIN] * wv);
}

__global__ __launch_bounds__(256) void k_z(
        const float* __restrict__ featd, const float* __restrict__ W_diff,
        const float* __restrict__ b_diff, float* __restrict__ z) {
    int row0 = blockIdx.x * 4;
    __shared__ float sF[4 * DIN];
    int tid = threadIdx.x;
    for (int i = tid; i < 4 * DIN / 4; i += 256)
        *(float4*)&sF[i * 4] = *(const float4*)&featd[(size_t)row0 * DIN + (size_t)i * 4];
    __syncthreads();
    int lr = tid >> 6, ch = tid & 63;
    const float* f = &sF[lr * DIN];
    float acc = b_diff[ch];
    for (int k = 0; k < DIN; k++) acc += f[k] * W_diff[k * HH + ch];
    z[(size_t)(row0 + lr) * HH + ch] = acc;
}

__global__ void k_dec(const float* __restrict__ z, const float* __restrict__ W_dec,
                      const float* __restrict__ b_dec, float* __restrict__ out) {
    size_t idx = (size_t)blockIdx.x * 256 + threadIdx.x;
    size_t row = idx / ODIM; int o = (int)(idx % ODIM);
    const float* zr = z + row * HH;
    float acc = b_dec[o];
    for (int k = 0; k < HH; k++) acc += zr[k] * W_dec[k * ODIM + o];
    int b = (int)(row >> 10), n = (int)(row & 1023);
    int t = o >> 3, f = o & 7;
    out[(((size_t)b * TT + t) * NN + n) * FF + f] = acc;
}

extern "C" void kernel_launch(void* const* d_in, const int* in_sizes, int n_in,
                              void* d_out, int out_size, void* d_ws, size_t ws_size,
                              hipStream_t stream) {
    const float* x      = (const float*)d_in[0];
    const int*   eiraw  = (const int*)  d_in[1];
    const float* ew     = (const float*)d_in[2];
    const float* adj    = (const float*)d_in[3];
    const float* W_enc  = (const float*)d_in[4];
    const float* b_enc  = (const float*)d_in[5];
    const float* emb    = (const float*)d_in[6];
    const float* W_r    = (const float*)d_in[7];
    const float* b_r    = (const float*)d_in[8];
    const float* W_u    = (const float*)d_in[9];
    const float* b_u    = (const float*)d_in[10];
    const float* W_c    = (const float*)d_in[11];
    const float* b_c    = (const float*)d_in[12];
    const float* W_diff = (const float*)d_in[13];
    const float* b_diff = (const float*)d_in[14];
    const float* W_dec  = (const float*)d_in[15];
    const float* b_dec  = (const float*)d_in[16];

    // ---- workspace: ~54.5 MiB (proven-safe up to 60.3 MiB from rounds 3/4) ----
    float* ws    = (float*)d_ws;
    float* rinv  = ws;                                   // 1024
    float* cinv  = rinv + NN;                            // 1024
    float* degd  = cinv + NN;                            // 1024
    float* degs  = degd + NN;                            // 1024
    float* wf    = degs + NN;                            // E
    float* wb    = wf + EE;                              // E
    int*   eifl  = (int*)(wb + EE);                      // 4
    int*   ei32  = eifl + 4;                             // 2E
    float* xh    = (float*)(ei32 + 2 * EE);              // B*N*128  (8 MiB)
    float* rh    = xh + (size_t)BB * NN * 128;           // B*N*64   (4 MiB)
    float* u_buf = rh + (size_t)BB * NN * HH;            // B*N*64   (4 MiB)
    float* feats = u_buf + (size_t)BB * NN * HH;         // B*N*512  (32 MiB)
    float* h     = feats + (size_t)BB * NN * FS;         // B*N*64   (4 MiB)
    float* featd = feats;   // alias: feats dead after GRU loop (20 <= 32 MiB)
    float* z     = xh;      // alias: xh dead after GRU loop

    hipMemsetAsync(h, 0, (size_t)BB * NN * HH * 4, stream);
    hipMemsetAsync(degd, 0, (size_t)2 * NN * 4, stream);

    k_ei_detect<<<1, 256, 0, stream>>>(eiraw, eifl);
    k_ei_norm<<<2 * EE / 256, 256, 0, stream>>>(eiraw, eifl, ei32);
    k_rowsum<<<NN, 256, 0, stream>>>(adj, rinv);
    k_colsum<<<NN / 256, 256, 0, stream>>>(adj, cinv);

    dim3 g2(16, 2, 32);   // hop on [x|h]: 1024 blocks
    dim3 g1(16, 1, 32);   // hop on rh:     512 blocks
    for (int t = 0; t < TT; t++) {
        k_enc2<<<BB * NN * 128 / 256, 256, 0, stream>>>(x, W_enc, b_enc, emb, h, xh, t);
        // hop1: A_s @ [x|h] -> feats cols s*256 + {0..127}
        k_hop<<<g2, 256, 0, stream>>>(adj, rinv, cinv, xh, 128, 0, 0, feats, 0);
        // hop2: A_s @ hop1 -> feats cols s*256 + {128..255}
        k_hop<<<g2, 256, 0, stream>>>(adj, rinv, cinv, feats, FS, 256, 0, feats, 128);
        // gates: r,u from feats@W; rh = sigmoid(r)*h
        k_gates<<<dim3(BB * NN / 64, 2), 256, 0, stream>>>(feats, W_r, W_u, b_r, b_u, h, rh, u_buf);
        // hop1rh: A_s @ rh -> overwrite h-part of hop1 (cols s*256 + 64..127)
        k_hop<<<g1, 256, 0, stream>>>(adj, rinv, cinv, rh, HH, 0, 0, feats, 64);
        // hop2rh: A_s @ hop1rh -> overwrite h-part of hop2 (cols s*256 + 192..255)
        k_hop<<<g1, 256, 0, stream>>>(adj, rinv, cinv, feats, FS, 256, 64, feats, 192);
        // candidate + state update
        k_cand<<<BB * NN / 32, 256, 0, stream>>>(feats, W_c, b_c, u_buf, h);
    }

    // ---- DiffConv readout ----
    k_deg<<<EE / 256, 256, 0, stream>>>(ei32, ew, degd, degs);
    k_wnorm<<<EE / 256, 256, 0, stream>>>(ei32, ew, degd, degs, wf, wb);
    k_featd_init<<<(BB * NN * DIN) / 256, 256, 0, stream>>>(h, featd);
    const int* srcp = ei32;
    const int* dstp = ei32 + EE;
    k_scatter<<<(EE * HH) / 256, 256, 0, stream>>>(featd, srcp, dstp, wf, 0, HH);
    k_scatter<<<(EE * HH) / 256, 256, 0, stream>>>(featd, srcp, dstp, wf, HH, 2 * HH);
    k_scatter<<<(EE * HH) / 256, 256, 0, stream>>>(featd, dstp, srcp, wb, 0, 3 * HH);
    k_scatter<<<(EE * HH) / 256, 256, 0, stream>>>(featd, dstp, srcp, wb, 3 * HH, 4 * HH);
    k_z<<<BB * NN / 4, 256, 0, stream>>>(featd, W_diff, b_diff, z);
    k_dec<<<(BB * NN * ODIM) / 256, 256, 0, stream>>>(z, W_dec, b_dec, (float*)d_out);
}

// Round 9
// 3400.849 us; speedup vs baseline: 5.8751x; 1.8627x over previous
//
#include <hip/hip_runtime.h>
#include <hip/hip_bf16.h>
#include <math.h>

#define BB 16
#define TT 12
#define NN 1024
#define FF 8
#define HH 64
#define EE 32768
#define DIN 320   // H * (2K+1)
#define ODIM 96   // F * HORIZON
#define FS 512    // feats row stride: [fwd1|fwd2|bwd1|bwd2] x [x|h](128)
#define APAD 40   // LDS row pad (ushort): 80B stride -> 16B-aligned b128, 2-way banks

typedef short v8s __attribute__((ext_vector_type(8)));
typedef float v4f __attribute__((ext_vector_type(4)));

__device__ __forceinline__ unsigned short f2bf_rne(float v) {
    unsigned u = __float_as_uint(v);
    u += 0x7FFF + ((u >> 16) & 1);
    return (unsigned short)(u >> 16);
}
__device__ __forceinline__ void split_bf(float v, unsigned short& hi, unsigned short& lo) {
    hi = f2bf_rne(v);
    float vh = __uint_as_float((unsigned)hi << 16);
    lo = f2bf_rne(v - vh);
}

// ---------------- edge_index insurance (proven int32; pass-through) ----------------
__global__ void k_ei_detect(const int* __restrict__ ei_raw, int* __restrict__ flag) {
    __shared__ int s[256];
    s[threadIdx.x] = ei_raw[2 * threadIdx.x + 1];
    __syncthreads();
    for (int st = 128; st > 0; st >>= 1) {
        if (threadIdx.x < st) s[threadIdx.x] |= s[threadIdx.x + st];
        __syncthreads();
    }
    if (threadIdx.x == 0) flag[0] = (s[0] == 0) ? 1 : 0;
}

__global__ void k_ei_norm(const int* __restrict__ ei_raw, const int* __restrict__ flag,
                          int* __restrict__ ei32) {
    int j = blockIdx.x * 256 + threadIdx.x;
    ei32[j] = flag[0] ? ei_raw[2 * j] : ei_raw[j];
}

// ---------------- support normalization ----------------
__global__ void k_rowsum(const float* __restrict__ adj, float* __restrict__ rinv) {
    __shared__ float s[256];
    int i = blockIdx.x;
    float acc = 0.f;
    for (int j = threadIdx.x; j < NN; j += 256) acc += adj[i * NN + j];
    s[threadIdx.x] = acc;
    __syncthreads();
    for (int st = 128; st > 0; st >>= 1) {
        if (threadIdx.x < st) s[threadIdx.x] += s[threadIdx.x + st];
        __syncthreads();
    }
    if (threadIdx.x == 0) rinv[i] = (s[0] != 0.f) ? 1.f / s[0] : 0.f;
}

__global__ void k_colsum(const float* __restrict__ adj, float* __restrict__ cinv) {
    int j = blockIdx.x * 256 + threadIdx.x;
    float acc = 0.f;
    for (int i = 0; i < NN; i++) acc += adj[i * NN + j];
    cinv[j] = (acc != 0.f) ? 1.f / acc : 0.f;
}

// ---------------- A matrices -> bf16 hi/lo, bwd pre-transposed ----------------
// Ah/Al layout: [s][w][v], s=0 fwd (adj[w][v]*rinv[w]), s=1 bwd (adj[v][w]*cinv[w]).
__global__ __launch_bounds__(256) void k_prepA(
        const float* __restrict__ adj, const float* __restrict__ rinv,
        const float* __restrict__ cinv,
        unsigned short* __restrict__ Ah, unsigned short* __restrict__ Al) {
    int w0 = blockIdx.x * 64, v0 = blockIdx.y * 64;
    __shared__ float T[64][68];
    int row = threadIdx.x >> 2, cs = (threadIdx.x & 3) * 16;
    #pragma unroll
    for (int j = 0; j < 4; j++)
        *(float4*)&T[row][cs + j * 4] = *(const float4*)(adj + (size_t)(w0 + row) * NN + v0 + cs + j * 4);
    __syncthreads();

    // fwd: A0[w0+row][v0+cs..+15]
    {
        float sc = rinv[w0 + row];
        unsigned hib[8], lob[8];
        #pragma unroll
        for (int j = 0; j < 8; j++) {
            unsigned short h0, l0, h1, l1;
            split_bf(T[row][cs + 2 * j] * sc, h0, l0);
            split_bf(T[row][cs + 2 * j + 1] * sc, h1, l1);
            hib[j] = (unsigned)h0 | ((unsigned)h1 << 16);
            lob[j] = (unsigned)l0 | ((unsigned)l1 << 16);
        }
        size_t ofs = (size_t)(w0 + row) * NN + v0 + cs;
        uint4* ph = (uint4*)(Ah + ofs);
        ph[0] = make_uint4(hib[0], hib[1], hib[2], hib[3]);
        ph[1] = make_uint4(hib[4], hib[5], hib[6], hib[7]);
        uint4* pl = (uint4*)(Al + ofs);
        pl[0] = make_uint4(lob[0], lob[1], lob[2], lob[3]);
        pl[1] = make_uint4(lob[4], lob[5], lob[6], lob[7]);
    }
    // bwd: A1[v0+row][w0+cs..+15] = T[cs+j][row] * cinv[v0+row]
    {
        float sc = cinv[v0 + row];
        unsigned hib[8], lob[8];
        #pragma unroll
        for (int j = 0; j < 8; j++) {
            unsigned short h0, l0, h1, l1;
            split_bf(T[cs + 2 * j][row] * sc, h0, l0);
            split_bf(T[cs + 2 * j + 1][row] * sc, h1, l1);
            hib[j] = (unsigned)h0 | ((unsigned)h1 << 16);
            lob[j] = (unsigned)l0 | ((unsigned)l1 << 16);
        }
        size_t ofs = (size_t)NN * NN + (size_t)(v0 + row) * NN + w0 + cs;
        uint4* ph = (uint4*)(Ah + ofs);
        ph[0] = make_uint4(hib[0], hib[1], hib[2], hib[3]);
        ph[1] = make_uint4(hib[4], hib[5], hib[6], hib[7]);
        uint4* pl = (uint4*)(Al + ofs);
        pl[0] = make_uint4(lob[0], lob[1], lob[2], lob[3]);
        pl[1] = make_uint4(lob[4], lob[5], lob[6], lob[7]);
    }
}

// ---------------- xh build: cols 0-63 = enc(x_t), 64-127 = h ----------------
__global__ void k_enc2(const float* __restrict__ x, const float* __restrict__ W_enc,
                       const float* __restrict__ b_enc, const float* __restrict__ emb,
                       const float* __restrict__ h, float* __restrict__ xh, int t) {
    size_t idx = (size_t)blockIdx.x * 256 + threadIdx.x;
    size_t row = idx >> 7; int c = (int)(idx & 127);
    if (c < HH) {
        int b = (int)(row >> 10), n = (int)(row & 1023);
        const float* xr = x + (((size_t)b * TT + t) * NN + n) * FF;
        float acc = b_enc[c] + emb[(size_t)n * HH + c];
        #pragma unroll
        for (int f = 0; f < FF; f++) acc += xr[f] * W_enc[f * HH + c];
        xh[idx] = acc;
    } else {
        xh[idx] = h[row * HH + (c - HH)];
    }
}

// ---------------- MFMA split-bf16 hop: Y = A_s @ X ----------------
// D = Ah*Xh + Ah*Xl + Al*Xh (f32 acc). Block 64x64, K=1024 in 32-chunks, 4 waves.
// grid (16 rowtiles, nct coltiles, BB*2); s = z&1 selects matrix, iso/oso col offsets.
__global__ __launch_bounds__(256) void k_mhop(
        const unsigned short* __restrict__ Ah, const unsigned short* __restrict__ Al,
        const float* __restrict__ Xin, int in_stride, int iso, int ico,
        float* __restrict__ Yout, int out_stride, int oso, int oco) {
    int zz = blockIdx.z;
    int b = zz >> 1, s = zz & 1;
    const unsigned short* Ahp = Ah + (size_t)s * NN * NN;
    const unsigned short* Alp = Al + (size_t)s * NN * NN;
    const float* X = Xin + (size_t)b * NN * in_stride + s * iso + ico + blockIdx.y * 64;
    float* Y = Yout + (size_t)b * NN * out_stride + s * oso + oco + blockIdx.y * 64;
    int w0 = blockIdx.x * 64;

    __shared__ unsigned short sAh[64][APAD];
    __shared__ unsigned short sAl[64][APAD];
    __shared__ unsigned short sXh[64][APAD];   // transposed: [col][k]
    __shared__ unsigned short sXl[64][APAD];

    int tid = threadIdx.x;
    int lane = tid & 63, wave = tid >> 6;
    int wr = (wave >> 1) * 32, wc = (wave & 1) * 32;
    int l15 = lane & 15, quad = lane >> 4;

    int arow = tid >> 2, akk = (tid & 3) * 8;      // A staging: 64 rows x 32 k
    int xkr = tid & 31, xc8 = (tid >> 5) * 8;      // X staging: 32 k x 64 cols

    v4f acc[2][2];
    #pragma unroll
    for (int i = 0; i < 2; i++)
        #pragma unroll
        for (int j = 0; j < 2; j++) { acc[i][j][0]=0.f; acc[i][j][1]=0.f; acc[i][j][2]=0.f; acc[i][j][3]=0.f; }

    for (int k0 = 0; k0 < NN; k0 += 32) {
        size_t aofs = (size_t)(w0 + arow) * NN + k0 + akk;
        *(uint4*)&sAh[arow][akk] = *(const uint4*)(Ahp + aofs);
        *(uint4*)&sAl[arow][akk] = *(const uint4*)(Alp + aofs);
        const float* px = X + (size_t)(k0 + xkr) * in_stride + xc8;
        float4 x0 = *(const float4*)px;
        float4 x1 = *(const float4*)(px + 4);
        float xv[8] = {x0.x, x0.y, x0.z, x0.w, x1.x, x1.y, x1.z, x1.w};
        #pragma unroll
        for (int j = 0; j < 8; j++) {
            unsigned short hi, lo;
            split_bf(xv[j], hi, lo);
            sXh[xc8 + j][xkr] = hi;
            sXl[xc8 + j][xkr] = lo;
        }
        __syncthreads();

        v8s ah0 = *(const v8s*)&sAh[wr + l15][quad * 8];
        v8s ah1 = *(const v8s*)&sAh[wr + 16 + l15][quad * 8];
        v8s al0 = *(const v8s*)&sAl[wr + l15][quad * 8];
        v8s al1 = *(const v8s*)&sAl[wr + 16 + l15][quad * 8];
        v8s bh0 = *(const v8s*)&sXh[wc + l15][quad * 8];
        v8s bh1 = *(const v8s*)&sXh[wc + 16 + l15][quad * 8];
        v8s bl0 = *(const v8s*)&sXl[wc + l15][quad * 8];
        v8s bl1 = *(const v8s*)&sXl[wc + 16 + l15][quad * 8];

        acc[0][0] = __builtin_amdgcn_mfma_f32_16x16x32_bf16(ah0, bh0, acc[0][0], 0, 0, 0);
        acc[0][1] = __builtin_amdgcn_mfma_f32_16x16x32_bf16(ah0, bh1, acc[0][1], 0, 0, 0);
        acc[1][0] = __builtin_amdgcn_mfma_f32_16x16x32_bf16(ah1, bh0, acc[1][0], 0, 0, 0);
        acc[1][1] = __builtin_amdgcn_mfma_f32_16x16x32_bf16(ah1, bh1, acc[1][1], 0, 0, 0);
        acc[0][0] = __builtin_amdgcn_mfma_f32_16x16x32_bf16(ah0, bl0, acc[0][0], 0, 0, 0);
        acc[0][1] = __builtin_amdgcn_mfma_f32_16x16x32_bf16(ah0, bl1, acc[0][1], 0, 0, 0);
        acc[1][0] = __builtin_amdgcn_mfma_f32_16x16x32_bf16(ah1, bl0, acc[1][0], 0, 0, 0);
        acc[1][1] = __builtin_amdgcn_mfma_f32_16x16x32_bf16(ah1, bl1, acc[1][1], 0, 0, 0);
        acc[0][0] = __builtin_amdgcn_mfma_f32_16x16x32_bf16(al0, bh0, acc[0][0], 0, 0, 0);
        acc[0][1] = __builtin_amdgcn_mfma_f32_16x16x32_bf16(al0, bh1, acc[0][1], 0, 0, 0);
        acc[1][0] = __builtin_amdgcn_mfma_f32_16x16x32_bf16(al1, bh0, acc[1][0], 0, 0, 0);
        acc[1][1] = __builtin_amdgcn_mfma_f32_16x16x32_bf16(al1, bh1, acc[1][1], 0, 0, 0);
        __syncthreads();
    }

    // C/D layout: col = lane&15, row = quad*4 + reg  [m89/m91 verified]
    #pragma unroll
    for (int i = 0; i < 2; i++)
        #pragma unroll
        for (int j = 0; j < 2; j++) {
            int rbase = w0 + wr + i * 16 + quad * 4;
            int cc = wc + j * 16 + l15;
            #pragma unroll
            for (int rr = 0; rr < 4; rr++)
                Y[(size_t)(rbase + rr) * out_stride + cc] = acc[i][j][rr];
        }
}

// ---------------- gates GEMM (f32): sigmoid(feats@W+b); ct=0 -> rh=r*h, ct=1 -> u ----------------
__global__ __launch_bounds__(256) void k_gates(
        const float* __restrict__ feats,
        const float* __restrict__ W_r, const float* __restrict__ W_u,
        const float* __restrict__ b_r, const float* __restrict__ b_u,
        const float* __restrict__ h,
        float* __restrict__ rh, float* __restrict__ u_buf) {
    int ct = blockIdx.y;
    int row0 = blockIdx.x * 64;
    const float* W = ct ? W_u : W_r;
    const float* bias = ct ? b_u : b_r;

    __shared__ float Fa[16][68];
    __shared__ float Wb[16][68];

    int tid = threadIdx.x;
    int ar = tid >> 2,  ak  = (tid & 3) * 4;
    int bk = tid >> 4,  bc4 = (tid & 15) * 4;
    int ty = tid >> 4,  tx  = tid & 15;

    float acc[4][4] = {};
    for (int k0 = 0; k0 < FS; k0 += 16) {
        float4 fv = *(const float4*)(feats + (size_t)(row0 + ar) * FS + k0 + ak);
        Fa[ak + 0][ar] = fv.x; Fa[ak + 1][ar] = fv.y;
        Fa[ak + 2][ar] = fv.z; Fa[ak + 3][ar] = fv.w;
        *(float4*)&Wb[bk][bc4] = *(const float4*)(W + (size_t)(k0 + bk) * HH + bc4);
        __syncthreads();
        #pragma unroll
        for (int kk = 0; kk < 16; kk++) {
            const float4 a4 = *(const float4*)&Fa[kk][ty * 4];
            const float4 b4 = *(const float4*)&Wb[kk][tx * 4];
            acc[0][0] += a4.x * b4.x; acc[0][1] += a4.x * b4.y; acc[0][2] += a4.x * b4.z; acc[0][3] += a4.x * b4.w;
            acc[1][0] += a4.y * b4.x; acc[1][1] += a4.y * b4.y; acc[1][2] += a4.y * b4.z; acc[1][3] += a4.y * b4.w;
            acc[2][0] += a4.z * b4.x; acc[2][1] += a4.z * b4.y; acc[2][2] += a4.z * b4.z; acc[2][3] += a4.z * b4.w;
            acc[3][0] += a4.w * b4.x; acc[3][1] += a4.w * b4.y; acc[3][2] += a4.w * b4.z; acc[3][3] += a4.w * b4.w;
        }
        __syncthreads();
    }
    #pragma unroll
    for (int i = 0; i < 4; i++) {
        size_t row = row0 + ty * 4 + i;
        #pragma unroll
        for (int j = 0; j < 4; j++) {
            int c = tx * 4 + j;
            float v = 1.f / (1.f + expf(-(acc[i][j] + bias[c])));
            if (ct == 0) rh[row * HH + c] = v * h[row * HH + c];
            else         u_buf[row * HH + c] = v;
        }
    }
}

// ---------------- candidate GEMM + h update ----------------
__global__ __launch_bounds__(256) void k_cand(
        const float* __restrict__ feats, const float* __restrict__ W_c,
        const float* __restrict__ b_c, const float* __restrict__ u_buf,
        float* __restrict__ h) {
    int row0 = blockIdx.x * 32;
    __shared__ float Fa[16][36];
    __shared__ float Wb[16][68];

    int tid = threadIdx.x;
    int ar = tid >> 3,  ak2 = (tid & 7) * 2;
    int bk = tid >> 4,  bc4 = (tid & 15) * 4;
    int ty = tid >> 4,  tx  = tid & 15;

    float acc[2][4] = {};
    for (int k0 = 0; k0 < FS; k0 += 16) {
        float2 fv = *(const float2*)(feats + (size_t)(row0 + ar) * FS + k0 + ak2);
        Fa[ak2 + 0][ar] = fv.x; Fa[ak2 + 1][ar] = fv.y;
        *(float4*)&Wb[bk][bc4] = *(const float4*)(W_c + (size_t)(k0 + bk) * HH + bc4);
        __syncthreads();
        #pragma unroll
        for (int kk = 0; kk < 16; kk++) {
            float a0 = Fa[kk][ty * 2 + 0];
            float a1 = Fa[kk][ty * 2 + 1];
            const float4 b4 = *(const float4*)&Wb[kk][tx * 4];
            acc[0][0] += a0 * b4.x; acc[0][1] += a0 * b4.y; acc[0][2] += a0 * b4.z; acc[0][3] += a0 * b4.w;
            acc[1][0] += a1 * b4.x; acc[1][1] += a1 * b4.y; acc[1][2] += a1 * b4.z; acc[1][3] += a1 * b4.w;
        }
        __syncthreads();
    }
    #pragma unroll
    for (int i = 0; i < 2; i++) {
        size_t row = row0 + ty * 2 + i;
        #pragma unroll
        for (int j = 0; j < 4; j++) {
            int c = tx * 4 + j;
            float cv = tanhf(acc[i][j] + b_c[c]);
            float u = u_buf[row * HH + c];
            float hv = h[row * HH + c];
            h[row * HH + c] = u * hv + (1.f - u) * cv;
        }
    }
}

// ---------------- DiffConv: dense sparse-operator build ----------------
__global__ void k_deg(const int* __restrict__ ei32, const float* __restrict__ ew,
                      float* __restrict__ degd, float* __restrict__ degs) {
    int e = blockIdx.x * 256 + threadIdx.x;
    float w = ew[e];
    atomicAdd(&degd[ei32[EE + e]], w);
    atomicAdd(&degs[ei32[e]], w);
}

// temp[0][dst][src] += ew/deg_dst;  temp[1][src][dst] += ew/deg_src
__global__ void k_spadd(const int* __restrict__ ei32, const float* __restrict__ ew,
                        const float* __restrict__ degd, const float* __restrict__ degs,
                        float* __restrict__ temp) {
    int e = blockIdx.x * 256 + threadIdx.x;
    int s = ei32[e], d = ei32[EE + e];
    float w = ew[e];
    float dd = degd[d], ds = degs[s];
    float wfv = dd > 0.f ? w / dd : 0.f;
    float wbv = ds > 0.f ? w / ds : 0.f;
    atomicAdd(&temp[(size_t)d * NN + s], wfv);
    atomicAdd(&temp[(size_t)NN * NN + (size_t)s * NN + d], wbv);
}

__global__ void k_spconv(const float* __restrict__ temp,
                         unsigned short* __restrict__ Ah, unsigned short* __restrict__ Al) {
    size_t i0 = ((size_t)blockIdx.x * 256 + threadIdx.x) * 8;
    unsigned short h8[8], l8[8];
    #pragma unroll
    for (int j = 0; j < 8; j++) split_bf(temp[i0 + j], h8[j], l8[j]);
    *(uint4*)(Ah + i0) = *(uint4*)h8;
    *(uint4*)(Al + i0) = *(uint4*)l8;
}

__global__ void k_featd_h(const float* __restrict__ h, float* __restrict__ featd) {
    size_t idx = (size_t)blockIdx.x * 256 + threadIdx.x;   // B*N*H
    size_t row = idx >> 6; int c = (int)(idx & 63);
    featd[row * DIN + c] = h[idx];
}

__global__ __launch_bounds__(256) void k_z(
        const float* __restrict__ featd, const float* __restrict__ W_diff,
        const float* __restrict__ b_diff, float* __restrict__ z) {
    int row0 = blockIdx.x * 4;
    __shared__ float sF[4 * DIN];
    int tid = threadIdx.x;
    for (int i = tid; i < 4 * DIN / 4; i += 256)
        *(float4*)&sF[i * 4] = *(const float4*)&featd[(size_t)row0 * DIN + (size_t)i * 4];
    __syncthreads();
    int lr = tid >> 6, ch = tid & 63;
    const float* f = &sF[lr * DIN];
    float acc = b_diff[ch];
    for (int k = 0; k < DIN; k++) acc += f[k] * W_diff[k * HH + ch];
    z[(size_t)(row0 + lr) * HH + ch] = acc;
}

__global__ void k_dec(const float* __restrict__ z, const float* __restrict__ W_dec,
                      const float* __restrict__ b_dec, float* __restrict__ out) {
    size_t idx = (size_t)blockIdx.x * 256 + threadIdx.x;
    size_t row = idx / ODIM; int o = (int)(idx % ODIM);
    const float* zr = z + row * HH;
    float acc = b_dec[o];
    for (int k = 0; k < HH; k++) acc += zr[k] * W_dec[k * ODIM + o];
    int b = (int)(row >> 10), n = (int)(row & 1023);
    int t = o >> 3, f = o & 7;
    out[(((size_t)b * TT + t) * NN + n) * FF + f] = acc;
}

extern "C" void kernel_launch(void* const* d_in, const int* in_sizes, int n_in,
                              void* d_out, int out_size, void* d_ws, size_t ws_size,
                              hipStream_t stream) {
    const float* x      = (const float*)d_in[0];
    const int*   eiraw  = (const int*)  d_in[1];
    const float* ew     = (const float*)d_in[2];
    const float* adj    = (const float*)d_in[3];
    const float* W_enc  = (const float*)d_in[4];
    const float* b_enc  = (const float*)d_in[5];
    const float* emb    = (const float*)d_in[6];
    const float* W_r    = (const float*)d_in[7];
    const float* b_r    = (const float*)d_in[8];
    const float* W_u    = (const float*)d_in[9];
    const float* b_u    = (const float*)d_in[10];
    const float* W_c    = (const float*)d_in[11];
    const float* b_c    = (const float*)d_in[12];
    const float* W_diff = (const float*)d_in[13];
    const float* b_diff = (const float*)d_in[14];
    const float* W_dec  = (const float*)d_in[15];
    const float* b_dec  = (const float*)d_in[16];

    // ---- workspace: ~60.3 MiB ----
    float* ws   = (float*)d_ws;
    int*   eifl = (int*)ws;                              // 4
    int*   ei32 = eifl + 4;                              // 2E
    float* rinv = (float*)(ei32 + 2 * EE);               // 1024
    float* cinv = rinv + NN;                             // 1024
    unsigned short* Ah = (unsigned short*)(cinv + NN);   // [2][N][N] bf16 hi (4 MiB)
    unsigned short* Al = Ah + (size_t)2 * NN * NN;       // [2][N][N] bf16 lo (4 MiB)
    float* xh    = (float*)(Al + (size_t)2 * NN * NN);   // B*N*128  (8 MiB)
    float* rh    = xh + (size_t)BB * NN * 128;           // B*N*64   (4 MiB)
    float* u_buf = rh + (size_t)BB * NN * HH;            // B*N*64   (4 MiB)
    float* feats = u_buf + (size_t)BB * NN * HH;         // B*N*512  (32 MiB)
    float* h     = feats + (size_t)BB * NN * FS;         // B*N*64   (4 MiB)
    // readout overlays (dead buffers after GRU loop):
    float* degd  = rh;                                   // 1024
    float* degs  = rh + NN;                              // 1024
    float* sptmp = feats + (size_t)BB * NN * DIN;        // 2*N*N f32 (8 MiB, feats tail)
    float* featd = feats;                                // B*N*320 (20 MiB)
    float* z     = xh;                                   // B*N*64

    hipMemsetAsync(h, 0, (size_t)BB * NN * HH * 4, stream);

    k_ei_detect<<<1, 256, 0, stream>>>(eiraw, eifl);
    k_ei_norm<<<2 * EE / 256, 256, 0, stream>>>(eiraw, eifl, ei32);
    k_rowsum<<<NN, 256, 0, stream>>>(adj, rinv);
    k_colsum<<<NN / 256, 256, 0, stream>>>(adj, cinv);
    k_prepA<<<dim3(16, 16), 256, 0, stream>>>(adj, rinv, cinv, Ah, Al);

    dim3 g2(16, 2, 32);   // hop on 128-col inputs
    dim3 g1(16, 1, 32);   // hop on 64-col inputs
    for (int t = 0; t < TT; t++) {
        k_enc2<<<BB * NN * 128 / 256, 256, 0, stream>>>(x, W_enc, b_enc, emb, h, xh, t);
        k_mhop<<<g2, 256, 0, stream>>>(Ah, Al, xh, 128, 0, 0, feats, FS, 256, 0);
        k_mhop<<<g2, 256, 0, stream>>>(Ah, Al, feats, FS, 256, 0, feats, FS, 256, 128);
        k_gates<<<dim3(BB * NN / 64, 2), 256, 0, stream>>>(feats, W_r, W_u, b_r, b_u, h, rh, u_buf);
        k_mhop<<<g1, 256, 0, stream>>>(Ah, Al, rh, HH, 0, 0, feats, FS, 256, 64);
        k_mhop<<<g1, 256, 0, stream>>>(Ah, Al, feats, FS, 256, 64, feats, FS, 256, 192);
        k_cand<<<BB * NN / 32, 256, 0, stream>>>(feats, W_c, b_c, u_buf, h);
    }

    // ---- DiffConv readout: densify sparse ops, reuse k_mhop ----
    hipMemsetAsync(degd, 0, (size_t)2 * NN * 4, stream);
    hipMemsetAsync(sptmp, 0, (size_t)2 * NN * NN * 4, stream);
    k_deg<<<EE / 256, 256, 0, stream>>>(ei32, ew, degd, degs);
    k_spadd<<<EE / 256, 256, 0, stream>>>(ei32, ew, degd, degs, sptmp);
    k_spconv<<<2 * NN * NN / (256 * 8), 256, 0, stream>>>(sptmp, Ah, Al);  // overwrite GRU A slots (dead)
    k_featd_h<<<BB * NN * HH / 256, 256, 0, stream>>>(h, featd);
    // hops: s=0 fwd -> cols 64(k1)/128(k2); s=1 bwd -> 192/256
    k_mhop<<<g1, 256, 0, stream>>>(Ah, Al, h, HH, 0, 0, featd, DIN, 128, 64);
    k_mhop<<<g1, 256, 0, stream>>>(Ah, Al, featd, DIN, 128, 64, featd, DIN, 128, 128);
    k_z<<<BB * NN / 4, 256, 0, stream>>>(featd, W_diff, b_diff, z);
    k_dec<<<(BB * NN * ODIM) / 256, 256, 0, stream>>>(z, W_dec, b_dec, (float*)d_out);
}

// Round 10
// 3360.960 us; speedup vs baseline: 5.9448x; 1.0119x over previous
//
#include <hip/hip_runtime.h>
#include <hip/hip_bf16.h>
#include <math.h>

#define BB 16
#define TT 12
#define NN 1024
#define FF 8
#define HH 64
#define EE 32768
#define DIN 320   // H * (2K+1)
#define ODIM 96   // F * HORIZON
#define FS 512    // feats row stride: [fwd|bwd] x [x1|rh1|x2|rh2](64 each)
#define APAD 40   // LDS row pad (ushort): 80B stride -> 16B-aligned b128

typedef short v8s __attribute__((ext_vector_type(8)));
typedef float v4f __attribute__((ext_vector_type(4)));

__device__ __forceinline__ unsigned short f2bf_rne(float v) {
    unsigned u = __float_as_uint(v);
    u += 0x7FFF + ((u >> 16) & 1);
    return (unsigned short)(u >> 16);
}
__device__ __forceinline__ void split_bf(float v, unsigned short& hi, unsigned short& lo) {
    hi = f2bf_rne(v);
    float vh = __uint_as_float((unsigned)hi << 16);
    lo = f2bf_rne(v - vh);
}

// ---------------- edge_index insurance (proven int32; pass-through) ----------------
__global__ void k_ei_detect(const int* __restrict__ ei_raw, int* __restrict__ flag) {
    __shared__ int s[256];
    s[threadIdx.x] = ei_raw[2 * threadIdx.x + 1];
    __syncthreads();
    for (int st = 128; st > 0; st >>= 1) {
        if (threadIdx.x < st) s[threadIdx.x] |= s[threadIdx.x + st];
        __syncthreads();
    }
    if (threadIdx.x == 0) flag[0] = (s[0] == 0) ? 1 : 0;
}

__global__ void k_ei_norm(const int* __restrict__ ei_raw, const int* __restrict__ flag,
                          int* __restrict__ ei32) {
    int j = blockIdx.x * 256 + threadIdx.x;
    ei32[j] = flag[0] ? ei_raw[2 * j] : ei_raw[j];
}

// ---------------- support normalization ----------------
__global__ void k_rowsum(const float* __restrict__ adj, float* __restrict__ rinv) {
    __shared__ float s[256];
    int i = blockIdx.x;
    float acc = 0.f;
    for (int j = threadIdx.x; j < NN; j += 256) acc += adj[i * NN + j];
    s[threadIdx.x] = acc;
    __syncthreads();
    for (int st = 128; st > 0; st >>= 1) {
        if (threadIdx.x < st) s[threadIdx.x] += s[threadIdx.x + st];
        __syncthreads();
    }
    if (threadIdx.x == 0) rinv[i] = (s[0] != 0.f) ? 1.f / s[0] : 0.f;
}

__global__ void k_colsum(const float* __restrict__ adj, float* __restrict__ cinv) {
    int j = blockIdx.x * 256 + threadIdx.x;
    float acc = 0.f;
    for (int i = 0; i < NN; i++) acc += adj[i * NN + j];
    cinv[j] = (acc != 0.f) ? 1.f / acc : 0.f;
}

// ---------------- A matrices -> bf16 hi/lo, bwd pre-transposed ----------------
__global__ __launch_bounds__(256) void k_prepA(
        const float* __restrict__ adj, const float* __restrict__ rinv,
        const float* __restrict__ cinv,
        unsigned short* __restrict__ Ah, unsigned short* __restrict__ Al) {
    int w0 = blockIdx.x * 64, v0 = blockIdx.y * 64;
    __shared__ float T[64][68];
    int row = threadIdx.x >> 2, cs = (threadIdx.x & 3) * 16;
    #pragma unroll
    for (int j = 0; j < 4; j++)
        *(float4*)&T[row][cs + j * 4] = *(const float4*)(adj + (size_t)(w0 + row) * NN + v0 + cs + j * 4);
    __syncthreads();
    {
        float sc = rinv[w0 + row];
        unsigned hib[8], lob[8];
        #pragma unroll
        for (int j = 0; j < 8; j++) {
            unsigned short h0, l0, h1, l1;
            split_bf(T[row][cs + 2 * j] * sc, h0, l0);
            split_bf(T[row][cs + 2 * j + 1] * sc, h1, l1);
            hib[j] = (unsigned)h0 | ((unsigned)h1 << 16);
            lob[j] = (unsigned)l0 | ((unsigned)l1 << 16);
        }
        size_t ofs = (size_t)(w0 + row) * NN + v0 + cs;
        uint4* ph = (uint4*)(Ah + ofs);
        ph[0] = make_uint4(hib[0], hib[1], hib[2], hib[3]);
        ph[1] = make_uint4(hib[4], hib[5], hib[6], hib[7]);
        uint4* pl = (uint4*)(Al + ofs);
        pl[0] = make_uint4(lob[0], lob[1], lob[2], lob[3]);
        pl[1] = make_uint4(lob[4], lob[5], lob[6], lob[7]);
    }
    {
        float sc = cinv[v0 + row];
        unsigned hib[8], lob[8];
        #pragma unroll
        for (int j = 0; j < 8; j++) {
            unsigned short h0, l0, h1, l1;
            split_bf(T[cs + 2 * j][row] * sc, h0, l0);
            split_bf(T[cs + 2 * j + 1][row] * sc, h1, l1);
            hib[j] = (unsigned)h0 | ((unsigned)h1 << 16);
            lob[j] = (unsigned)l0 | ((unsigned)l1 << 16);
        }
        size_t ofs = (size_t)NN * NN + (size_t)(v0 + row) * NN + w0 + cs;
        uint4* ph = (uint4*)(Ah + ofs);
        ph[0] = make_uint4(hib[0], hib[1], hib[2], hib[3]);
        ph[1] = make_uint4(hib[4], hib[5], hib[6], hib[7]);
        uint4* pl = (uint4*)(Al + ofs);
        pl[0] = make_uint4(lob[0], lob[1], lob[2], lob[3]);
        pl[1] = make_uint4(lob[4], lob[5], lob[6], lob[7]);
    }
}

// ---------------- xh build ----------------
__global__ void k_enc2(const float* __restrict__ x, const float* __restrict__ W_enc,
                       const float* __restrict__ b_enc, const float* __restrict__ emb,
                       const float* __restrict__ h, float* __restrict__ xh, int t) {
    size_t idx = (size_t)blockIdx.x * 256 + threadIdx.x;
    size_t row = idx >> 7; int c = (int)(idx & 127);
    if (c < HH) {
        int b = (int)(row >> 10), n = (int)(row & 1023);
        const float* xr = x + (((size_t)b * TT + t) * NN + n) * FF;
        float acc = b_enc[c] + emb[(size_t)n * HH + c];
        #pragma unroll
        for (int f = 0; f < FF; f++) acc += xr[f] * W_enc[f * HH + c];
        xh[idx] = acc;
    } else {
        xh[idx] = h[row * HH + (c - HH)];
    }
}

// ---------------- MFMA split-bf16 hop, 64x128 tile ----------------
// grid (16, 1, 32), zz: s = zz>>4 (s-major for L2 A-residency), b = zz&15.
__global__ __launch_bounds__(256) void k_mhop128(
        const unsigned short* __restrict__ Ah, const unsigned short* __restrict__ Al,
        const float* __restrict__ Xin, int in_stride, int iso,
        float* __restrict__ Yout, int out_stride, int oso, int oco) {
    int zz = blockIdx.z;
    int s = zz >> 4, b = zz & 15;
    const unsigned short* Ahp = Ah + (size_t)s * NN * NN;
    const unsigned short* Alp = Al + (size_t)s * NN * NN;
    const float* X = Xin + (size_t)b * NN * in_stride + s * iso;
    float* Y = Yout + (size_t)b * NN * out_stride + s * oso + oco;
    int w0 = blockIdx.x * 64;

    __shared__ unsigned short sAh[64][APAD];
    __shared__ unsigned short sAl[64][APAD];
    __shared__ unsigned short sXh[128][APAD];
    __shared__ unsigned short sXl[128][APAD];

    int tid = threadIdx.x;
    int lane = tid & 63, wave = tid >> 6;
    int wr = (wave >> 1) * 32, wc = (wave & 1) * 64;
    int l15 = lane & 15, quad = lane >> 4;
    int arow = tid >> 2, akk = (tid & 3) * 8;
    int xkr = tid & 31, xc16 = (tid >> 5) * 16;

    v4f acc[2][4];
    #pragma unroll
    for (int i = 0; i < 2; i++)
        #pragma unroll
        for (int j = 0; j < 4; j++) { acc[i][j][0]=0.f; acc[i][j][1]=0.f; acc[i][j][2]=0.f; acc[i][j][3]=0.f; }

    for (int k0 = 0; k0 < NN; k0 += 32) {
        size_t aofs = (size_t)(w0 + arow) * NN + k0 + akk;
        *(uint4*)&sAh[arow][akk] = *(const uint4*)(Ahp + aofs);
        *(uint4*)&sAl[arow][akk] = *(const uint4*)(Alp + aofs);
        const float* px = X + (size_t)(k0 + xkr) * in_stride + xc16;
        float4 x0 = *(const float4*)px;
        float4 x1 = *(const float4*)(px + 4);
        float4 x2 = *(const float4*)(px + 8);
        float4 x3 = *(const float4*)(px + 12);
        float xv[16] = {x0.x,x0.y,x0.z,x0.w, x1.x,x1.y,x1.z,x1.w,
                        x2.x,x2.y,x2.z,x2.w, x3.x,x3.y,x3.z,x3.w};
        #pragma unroll
        for (int j = 0; j < 16; j++) {
            unsigned short hi, lo;
            split_bf(xv[j], hi, lo);
            sXh[xc16 + j][xkr] = hi;
            sXl[xc16 + j][xkr] = lo;
        }
        __syncthreads();

        v8s ah0 = *(const v8s*)&sAh[wr + l15][quad * 8];
        v8s ah1 = *(const v8s*)&sAh[wr + 16 + l15][quad * 8];
        v8s al0 = *(const v8s*)&sAl[wr + l15][quad * 8];
        v8s al1 = *(const v8s*)&sAl[wr + 16 + l15][quad * 8];
        #pragma unroll
        for (int j = 0; j < 4; j++) {
            v8s bh = *(const v8s*)&sXh[wc + j * 16 + l15][quad * 8];
            v8s bl = *(const v8s*)&sXl[wc + j * 16 + l15][quad * 8];
            acc[0][j] = __builtin_amdgcn_mfma_f32_16x16x32_bf16(ah0, bh, acc[0][j], 0, 0, 0);
            acc[1][j] = __builtin_amdgcn_mfma_f32_16x16x32_bf16(ah1, bh, acc[1][j], 0, 0, 0);
            acc[0][j] = __builtin_amdgcn_mfma_f32_16x16x32_bf16(ah0, bl, acc[0][j], 0, 0, 0);
            acc[1][j] = __builtin_amdgcn_mfma_f32_16x16x32_bf16(ah1, bl, acc[1][j], 0, 0, 0);
            acc[0][j] = __builtin_amdgcn_mfma_f32_16x16x32_bf16(al0, bh, acc[0][j], 0, 0, 0);
            acc[1][j] = __builtin_amdgcn_mfma_f32_16x16x32_bf16(al1, bh, acc[1][j], 0, 0, 0);
        }
        __syncthreads();
    }

    #pragma unroll
    for (int i = 0; i < 2; i++)
        #pragma unroll
        for (int j = 0; j < 4; j++) {
            int rbase = w0 + wr + i * 16 + quad * 4;
            int cc = wc + j * 16 + l15;
            #pragma unroll
            for (int rr = 0; rr < 4; rr++)
                Y[(size_t)(rbase + rr) * out_stride + cc] = acc[i][j][rr];
        }
}

// ---------------- MFMA split-bf16 hop, 64x64 tile (64-col inputs) ----------------
__global__ __launch_bounds__(256) void k_mhop64(
        const unsigned short* __restrict__ Ah, const unsigned short* __restrict__ Al,
        const float* __restrict__ Xin, int in_stride, int iso, int ico,
        float* __restrict__ Yout, int out_stride, int oso, int oco) {
    int zz = blockIdx.z;
    int s = zz >> 4, b = zz & 15;
    const unsigned short* Ahp = Ah + (size_t)s * NN * NN;
    const unsigned short* Alp = Al + (size_t)s * NN * NN;
    const float* X = Xin + (size_t)b * NN * in_stride + s * iso + ico;
    float* Y = Yout + (size_t)b * NN * out_stride + s * oso + oco;
    int w0 = blockIdx.x * 64;

    __shared__ unsigned short sAh[64][APAD];
    __shared__ unsigned short sAl[64][APAD];
    __shared__ unsigned short sXh[64][APAD];
    __shared__ unsigned short sXl[64][APAD];

    int tid = threadIdx.x;
    int lane = tid & 63, wave = tid >> 6;
    int wr = (wave >> 1) * 32, wc = (wave & 1) * 32;
    int l15 = lane & 15, quad = lane >> 4;
    int arow = tid >> 2, akk = (tid & 3) * 8;
    int xkr = tid & 31, xc8 = (tid >> 5) * 8;

    v4f acc[2][2];
    #pragma unroll
    for (int i = 0; i < 2; i++)
        #pragma unroll
        for (int j = 0; j < 2; j++) { acc[i][j][0]=0.f; acc[i][j][1]=0.f; acc[i][j][2]=0.f; acc[i][j][3]=0.f; }

    for (int k0 = 0; k0 < NN; k0 += 32) {
        size_t aofs = (size_t)(w0 + arow) * NN + k0 + akk;
        *(uint4*)&sAh[arow][akk] = *(const uint4*)(Ahp + aofs);
        *(uint4*)&sAl[arow][akk] = *(const uint4*)(Alp + aofs);
        const float* px = X + (size_t)(k0 + xkr) * in_stride + xc8;
        float4 x0 = *(const float4*)px;
        float4 x1 = *(const float4*)(px + 4);
        float xv[8] = {x0.x, x0.y, x0.z, x0.w, x1.x, x1.y, x1.z, x1.w};
        #pragma unroll
        for (int j = 0; j < 8; j++) {
            unsigned short hi, lo;
            split_bf(xv[j], hi, lo);
            sXh[xc8 + j][xkr] = hi;
            sXl[xc8 + j][xkr] = lo;
        }
        __syncthreads();

        v8s ah0 = *(const v8s*)&sAh[wr + l15][quad * 8];
        v8s ah1 = *(const v8s*)&sAh[wr + 16 + l15][quad * 8];
        v8s al0 = *(const v8s*)&sAl[wr + l15][quad * 8];
        v8s al1 = *(const v8s*)&sAl[wr + 16 + l15][quad * 8];
        #pragma unroll
        for (int j = 0; j < 2; j++) {
            v8s bh = *(const v8s*)&sXh[wc + j * 16 + l15][quad * 8];
            v8s bl = *(const v8s*)&sXl[wc + j * 16 + l15][quad * 8];
            acc[0][j] = __builtin_amdgcn_mfma_f32_16x16x32_bf16(ah0, bh, acc[0][j], 0, 0, 0);
            acc[1][j] = __builtin_amdgcn_mfma_f32_16x16x32_bf16(ah1, bh, acc[1][j], 0, 0, 0);
            acc[0][j] = __builtin_amdgcn_mfma_f32_16x16x32_bf16(ah0, bl, acc[0][j], 0, 0, 0);
            acc[1][j] = __builtin_amdgcn_mfma_f32_16x16x32_bf16(ah1, bl, acc[1][j], 0, 0, 0);
            acc[0][j] = __builtin_amdgcn_mfma_f32_16x16x32_bf16(al0, bh, acc[0][j], 0, 0, 0);
            acc[1][j] = __builtin_amdgcn_mfma_f32_16x16x32_bf16(al1, bh, acc[1][j], 0, 0, 0);
        }
        __syncthreads();
    }

    #pragma unroll
    for (int i = 0; i < 2; i++)
        #pragma unroll
        for (int j = 0; j < 2; j++) {
            int rbase = w0 + wr + i * 16 + quad * 4;
            int cc = wc + j * 16 + l15;
            #pragma unroll
            for (int rr = 0; rr < 4; rr++)
                Y[(size_t)(rbase + rr) * out_stride + cc] = acc[i][j][rr];
        }
}

// ---------------- merged gates GEMM: r AND u per block (feats read once) ----------------
// grid 512 blocks x 32 rows
__global__ __launch_bounds__(256) void k_gates(
        const float* __restrict__ feats,
        const float* __restrict__ W_r, const float* __restrict__ W_u,
        const float* __restrict__ b_r, const float* __restrict__ b_u,
        const float* __restrict__ h,
        float* __restrict__ rh, float* __restrict__ u_buf) {
    int row0 = blockIdx.x * 32;
    __shared__ float Fa[16][36];
    __shared__ float Wr[16][68];
    __shared__ float Wu[16][68];

    int tid = threadIdx.x;
    int ar = tid >> 3,  ak2 = (tid & 7) * 2;
    int bk = tid >> 4,  bc4 = (tid & 15) * 4;
    int ty = tid >> 4,  tx  = tid & 15;

    float accr[2][4] = {}, accu[2][4] = {};
    for (int k0 = 0; k0 < FS; k0 += 16) {
        float2 fv = *(const float2*)(feats + (size_t)(row0 + ar) * FS + k0 + ak2);
        Fa[ak2 + 0][ar] = fv.x; Fa[ak2 + 1][ar] = fv.y;
        *(float4*)&Wr[bk][bc4] = *(const float4*)(W_r + (size_t)(k0 + bk) * HH + bc4);
        *(float4*)&Wu[bk][bc4] = *(const float4*)(W_u + (size_t)(k0 + bk) * HH + bc4);
        __syncthreads();
        #pragma unroll
        for (int kk = 0; kk < 16; kk++) {
            float a0 = Fa[kk][ty * 2 + 0];
            float a1 = Fa[kk][ty * 2 + 1];
            const float4 r4 = *(const float4*)&Wr[kk][tx * 4];
            const float4 u4 = *(const float4*)&Wu[kk][tx * 4];
            accr[0][0] += a0 * r4.x; accr[0][1] += a0 * r4.y; accr[0][2] += a0 * r4.z; accr[0][3] += a0 * r4.w;
            accr[1][0] += a1 * r4.x; accr[1][1] += a1 * r4.y; accr[1][2] += a1 * r4.z; accr[1][3] += a1 * r4.w;
            accu[0][0] += a0 * u4.x; accu[0][1] += a0 * u4.y; accu[0][2] += a0 * u4.z; accu[0][3] += a0 * u4.w;
            accu[1][0] += a1 * u4.x; accu[1][1] += a1 * u4.y; accu[1][2] += a1 * u4.z; accu[1][3] += a1 * u4.w;
        }
        __syncthreads();
    }
    #pragma unroll
    for (int i = 0; i < 2; i++) {
        size_t row = row0 + ty * 2 + i;
        #pragma unroll
        for (int j = 0; j < 4; j++) {
            int c = tx * 4 + j;
            float r = 1.f / (1.f + expf(-(accr[i][j] + b_r[c])));
            float u = 1.f / (1.f + expf(-(accu[i][j] + b_u[c])));
            rh[row * HH + c] = r * h[row * HH + c];
            u_buf[row * HH + c] = u;
        }
    }
}

// ---------------- candidate GEMM + h update ----------------
__global__ __launch_bounds__(256) void k_cand(
        const float* __restrict__ feats, const float* __restrict__ W_c,
        const float* __restrict__ b_c, const float* __restrict__ u_buf,
        float* __restrict__ h) {
    int row0 = blockIdx.x * 32;
    __shared__ float Fa[16][36];
    __shared__ float Wb[16][68];

    int tid = threadIdx.x;
    int ar = tid >> 3,  ak2 = (tid & 7) * 2;
    int bk = tid >> 4,  bc4 = (tid & 15) * 4;
    int ty = tid >> 4,  tx  = tid & 15;

    float acc[2][4] = {};
    for (int k0 = 0; k0 < FS; k0 += 16) {
        float2 fv = *(const float2*)(feats + (size_t)(row0 + ar) * FS + k0 + ak2);
        Fa[ak2 + 0][ar] = fv.x; Fa[ak2 + 1][ar] = fv.y;
        *(float4*)&Wb[bk][bc4] = *(const float4*)(W_c + (size_t)(k0 + bk) * HH + bc4);
        __syncthreads();
        #pragma unroll
        for (int kk = 0; kk < 16; kk++) {
            float a0 = Fa[kk][ty * 2 + 0];
            float a1 = Fa[kk][ty * 2 + 1];
            const float4 b4 = *(const float4*)&Wb[kk][tx * 4];
            acc[0][0] += a0 * b4.x; acc[0][1] += a0 * b4.y; acc[0][2] += a0 * b4.z; acc[0][3] += a0 * b4.w;
            acc[1][0] += a1 * b4.x; acc[1][1] += a1 * b4.y; acc[1][2] += a1 * b4.z; acc[1][3] += a1 * b4.w;
        }
        __syncthreads();
    }
    #pragma unroll
    for (int i = 0; i < 2; i++) {
        size_t row = row0 + ty * 2 + i;
        #pragma unroll
        for (int j = 0; j < 4; j++) {
            int c = tx * 4 + j;
            float cv = tanhf(acc[i][j] + b_c[c]);
            float u = u_buf[row * HH + c];
            float hv = h[row * HH + c];
            h[row * HH + c] = u * hv + (1.f - u) * cv;
        }
    }
}

// ---------------- DiffConv: dense sparse-operator build ----------------
__global__ void k_deg(const int* __restrict__ ei32, const float* __restrict__ ew,
                      float* __restrict__ degd, float* __restrict__ degs) {
    int e = blockIdx.x * 256 + threadIdx.x;
    float w = ew[e];
    atomicAdd(&degd[ei32[EE + e]], w);
    atomicAdd(&degs[ei32[e]], w);
}

__global__ void k_spadd(const int* __restrict__ ei32, const float* __restrict__ ew,
                        const float* __restrict__ degd, const float* __restrict__ degs,
                        float* __restrict__ temp) {
    int e = blockIdx.x * 256 + threadIdx.x;
    int s = ei32[e], d = ei32[EE + e];
    float w = ew[e];
    float dd = degd[d], ds = degs[s];
    float wfv = dd > 0.f ? w / dd : 0.f;
    float wbv = ds > 0.f ? w / ds : 0.f;
    atomicAdd(&temp[(size_t)d * NN + s], wfv);
    atomicAdd(&temp[(size_t)NN * NN + (size_t)s * NN + d], wbv);
}

__global__ void k_spconv(const float* __restrict__ temp,
                         unsigned short* __restrict__ Ah, unsigned short* __restrict__ Al) {
    size_t i0 = ((size_t)blockIdx.x * 256 + threadIdx.x) * 8;
    unsigned short h8[8], l8[8];
    #pragma unroll
    for (int j = 0; j < 8; j++) split_bf(temp[i0 + j], h8[j], l8[j]);
    *(uint4*)(Ah + i0) = *(uint4*)h8;
    *(uint4*)(Al + i0) = *(uint4*)l8;
}

__global__ void k_featd_h(const float* __restrict__ h, float* __restrict__ featd) {
    size_t idx = (size_t)blockIdx.x * 256 + threadIdx.x;
    size_t row = idx >> 6; int c = (int)(idx & 63);
    featd[row * DIN + c] = h[idx];
}

__global__ __launch_bounds__(256) void k_z(
        const float* __restrict__ featd, const float* __restrict__ W_diff,
        const float* __restrict__ b_diff, float* __restrict__ z) {
    int row0 = blockIdx.x * 4;
    __shared__ float sF[4 * DIN];
    int tid = threadIdx.x;
    for (int i = tid; i < 4 * DIN / 4; i += 256)
        *(float4*)&sF[i * 4] = *(const float4*)&featd[(size_t)row0 * DIN + (size_t)i * 4];
    __syncthreads();
    int lr = tid >> 6, ch = tid & 63;
    const float* f = &sF[lr * DIN];
    float acc = b_diff[ch];
    for (int k = 0; k < DIN; k++) acc += f[k] * W_diff[k * HH + ch];
    z[(size_t)(row0 + lr) * HH + ch] = acc;
}

__global__ void k_dec(const float* __restrict__ z, const float* __restrict__ W_dec,
                      const float* __restrict__ b_dec, float* __restrict__ out) {
    size_t idx = (size_t)blockIdx.x * 256 + threadIdx.x;
    size_t row = idx / ODIM; int o = (int)(idx % ODIM);
    const float* zr = z + row * HH;
    float acc = b_dec[o];
    for (int k = 0; k < HH; k++) acc += zr[k] * W_dec[k * ODIM + o];
    int b = (int)(row >> 10), n = (int)(row & 1023);
    int t = o >> 3, f = o & 7;
    out[(((size_t)b * TT + t) * NN + n) * FF + f] = acc;
}

extern "C" void kernel_launch(void* const* d_in, const int* in_sizes, int n_in,
                              void* d_out, int out_size, void* d_ws, size_t ws_size,
                              hipStream_t stream) {
    const float* x      = (const float*)d_in[0];
    const int*   eiraw  = (const int*)  d_in[1];
    const float* ew     = (const float*)d_in[2];
    const float* adj    = (const float*)d_in[3];
    const float* W_enc  = (const float*)d_in[4];
    const float* b_enc  = (const float*)d_in[5];
    const float* emb    = (const float*)d_in[6];
    const float* W_r    = (const float*)d_in[7];
    const float* b_r    = (const float*)d_in[8];
    const float* W_u    = (const float*)d_in[9];
    const float* b_u    = (const float*)d_in[10];
    const float* W_c    = (const float*)d_in[11];
    const float* b_c    = (const float*)d_in[12];
    const float* W_diff = (const float*)d_in[13];
    const float* b_diff = (const float*)d_in[14];
    const float* W_dec  = (const float*)d_in[15];
    const float* b_dec  = (const float*)d_in[16];

    float* ws   = (float*)d_ws;
    int*   eifl = (int*)ws;
    int*   ei32 = eifl + 4;
    float* rinv = (float*)(ei32 + 2 * EE);
    float* cinv = rinv + NN;
    unsigned short* Ah = (unsigned short*)(cinv + NN);   // [2][N][N] bf16 hi (4 MiB)
    unsigned short* Al = Ah + (size_t)2 * NN * NN;       // 4 MiB
    float* xh    = (float*)(Al + (size_t)2 * NN * NN);   // B*N*128  (8 MiB)
    float* rh    = xh + (size_t)BB * NN * 128;           // B*N*64
    float* u_buf = rh + (size_t)BB * NN * HH;            // B*N*64
    float* feats = u_buf + (size_t)BB * NN * HH;         // B*N*512  (32 MiB)
    float* h     = feats + (size_t)BB * NN * FS;         // B*N*64
    float* degd  = rh;
    float* degs  = rh + NN;
    float* sptmp = feats + (size_t)BB * NN * DIN;        // 2*N*N f32 (feats tail)
    float* featd = feats;
    float* z     = xh;

    hipMemsetAsync(h, 0, (size_t)BB * NN * HH * 4, stream);

    k_ei_detect<<<1, 256, 0, stream>>>(eiraw, eifl);
    k_ei_norm<<<2 * EE / 256, 256, 0, stream>>>(eiraw, eifl, ei32);
    k_rowsum<<<NN, 256, 0, stream>>>(adj, rinv);
    k_colsum<<<NN / 256, 256, 0, stream>>>(adj, cinv);
    k_prepA<<<dim3(16, 16), 256, 0, stream>>>(adj, rinv, cinv, Ah, Al);

    dim3 gh(16, 1, 32);
    for (int t = 0; t < TT; t++) {
        k_enc2<<<BB * NN * 128 / 256, 256, 0, stream>>>(x, W_enc, b_enc, emb, h, xh, t);
        // hop1: A_s @ [x|h](128c) -> feats cols s*256 + 0..127
        k_mhop128<<<gh, 256, 0, stream>>>(Ah, Al, xh, 128, 0, feats, FS, 256, 0);
        // hop2: A_s @ hop1 -> feats cols s*256 + 128..255
        k_mhop128<<<gh, 256, 0, stream>>>(Ah, Al, feats, FS, 256, feats, FS, 256, 128);
        // gates r+u merged; rh = sigmoid(r)*h
        k_gates<<<BB * NN / 32, 256, 0, stream>>>(feats, W_r, W_u, b_r, b_u, h, rh, u_buf);
        // hop1rh -> overwrite cols s*256 + 64..127 ; hop2rh -> s*256 + 192..255
        k_mhop64<<<gh, 256, 0, stream>>>(Ah, Al, rh, HH, 0, 0, feats, FS, 256, 64);
        k_mhop64<<<gh, 256, 0, stream>>>(Ah, Al, feats, FS, 256, 64, feats, FS, 256, 192);
        k_cand<<<BB * NN / 32, 256, 0, stream>>>(feats, W_c, b_c, u_buf, h);
    }

    // ---- DiffConv readout ----
    hipMemsetAsync(degd, 0, (size_t)2 * NN * 4, stream);
    hipMemsetAsync(sptmp, 0, (size_t)2 * NN * NN * 4, stream);
    k_deg<<<EE / 256, 256, 0, stream>>>(ei32, ew, degd, degs);
    k_spadd<<<EE / 256, 256, 0, stream>>>(ei32, ew, degd, degs, sptmp);
    k_spconv<<<2 * NN * NN / (256 * 8), 256, 0, stream>>>(sptmp, Ah, Al);
    k_featd_h<<<BB * NN * HH / 256, 256, 0, stream>>>(h, featd);
    k_mhop64<<<gh, 256, 0, stream>>>(Ah, Al, h, HH, 0, 0, featd, DIN, 128, 64);
    k_mhop64<<<gh, 256, 0, stream>>>(Ah, Al, featd, DIN, 128, 64, featd, DIN, 128, 128);
    k_z<<<BB * NN / 4, 256, 0, stream>>>(featd, W_diff, b_diff, z);
    k_dec<<<(BB * NN * ODIM) / 256, 256, 0, stream>>>(z, W_dec, b_dec, (float*)d_out);
}

// Round 12
// 3011.449 us; speedup vs baseline: 6.6348x; 1.1161x over previous
//
#include <hip/hip_runtime.h>
#include <hip/hip_bf16.h>
#include <math.h>

#define BB 16
#define TT 12
#define NN 1024
#define FF 8
#define HH 64
#define EE 32768
#define DIN 320   // H * (2K+1)
#define ODIM 96   // F * HORIZON
#define FS 512    // feats cols: [Af|Af2|Ab|Ab2] x [x(64)|h(64)]
#define APAD 40

// Injective LDS swizzle (ushort units). Row stride APAD=40 > 32 = k-span, and the
// XOR chunk permutation is a per-row bijection of [0,32) -> no collisions.
// XC: chunk-aligned base (kc multiple of 8). XE: per-element.
__device__ __forceinline__ int XC(int r, int kc) { return r * APAD + ((((kc) >> 3) ^ (r & 3)) << 3); }
__device__ __forceinline__ int XE(int r, int k)  { return XC(r, k) + (k & 7); }

typedef short v8s __attribute__((ext_vector_type(8)));
typedef float v4f __attribute__((ext_vector_type(4)));

__device__ __forceinline__ unsigned short f2bf_rne(float v) {
    unsigned u = __float_as_uint(v);
    u += 0x7FFF + ((u >> 16) & 1);
    return (unsigned short)(u >> 16);
}
__device__ __forceinline__ void split_bf(float v, unsigned short& hi, unsigned short& lo) {
    hi = f2bf_rne(v);
    float vh = __uint_as_float((unsigned)hi << 16);
    lo = f2bf_rne(v - vh);
}

// ---------------- edge_index insurance ----------------
__global__ void k_ei_detect(const int* __restrict__ ei_raw, int* __restrict__ flag) {
    __shared__ int s[256];
    s[threadIdx.x] = ei_raw[2 * threadIdx.x + 1];
    __syncthreads();
    for (int st = 128; st > 0; st >>= 1) {
        if (threadIdx.x < st) s[threadIdx.x] |= s[threadIdx.x + st];
        __syncthreads();
    }
    if (threadIdx.x == 0) flag[0] = (s[0] == 0) ? 1 : 0;
}
__global__ void k_ei_norm(const int* __restrict__ ei_raw, const int* __restrict__ flag,
                          int* __restrict__ ei32) {
    int j = blockIdx.x * 256 + threadIdx.x;
    ei32[j] = flag[0] ? ei_raw[2 * j] : ei_raw[j];
}

// ---------------- support normalization ----------------
__global__ void k_rowsum(const float* __restrict__ adj, float* __restrict__ rinv) {
    __shared__ float s[256];
    int i = blockIdx.x;
    float acc = 0.f;
    for (int j = threadIdx.x; j < NN; j += 256) acc += adj[i * NN + j];
    s[threadIdx.x] = acc;
    __syncthreads();
    for (int st = 128; st > 0; st >>= 1) {
        if (threadIdx.x < st) s[threadIdx.x] += s[threadIdx.x + st];
        __syncthreads();
    }
    if (threadIdx.x == 0) rinv[i] = (s[0] != 0.f) ? 1.f / s[0] : 0.f;
}
__global__ void k_colsum(const float* __restrict__ adj, float* __restrict__ cinv) {
    int j = blockIdx.x * 256 + threadIdx.x;
    float acc = 0.f;
    for (int i = 0; i < NN; i++) acc += adj[i * NN + j];
    cinv[j] = (acc != 0.f) ? 1.f / acc : 0.f;
}

// ---------------- Af -> M rows 0..1023, Ab -> M rows 2048..3071 (split bf16) ----------------
__global__ __launch_bounds__(256) void k_prepA(
        const float* __restrict__ adj, const float* __restrict__ rinv,
        const float* __restrict__ cinv,
        unsigned short* __restrict__ Mh, unsigned short* __restrict__ Ml) {
    int w0 = blockIdx.x * 64, v0 = blockIdx.y * 64;
    __shared__ float T[64][68];
    int row = threadIdx.x >> 2, cs = (threadIdx.x & 3) * 16;
    #pragma unroll
    for (int j = 0; j < 4; j++)
        *(float4*)&T[row][cs + j * 4] = *(const float4*)(adj + (size_t)(w0 + row) * NN + v0 + cs + j * 4);
    __syncthreads();
    {
        float sc = rinv[w0 + row];
        unsigned hib[8], lob[8];
        #pragma unroll
        for (int j = 0; j < 8; j++) {
            unsigned short h0, l0, h1, l1;
            split_bf(T[row][cs + 2 * j] * sc, h0, l0);
            split_bf(T[row][cs + 2 * j + 1] * sc, h1, l1);
            hib[j] = (unsigned)h0 | ((unsigned)h1 << 16);
            lob[j] = (unsigned)l0 | ((unsigned)l1 << 16);
        }
        size_t ofs = (size_t)(w0 + row) * NN + v0 + cs;
        ((uint4*)(Mh + ofs))[0] = make_uint4(hib[0], hib[1], hib[2], hib[3]);
        ((uint4*)(Mh + ofs))[1] = make_uint4(hib[4], hib[5], hib[6], hib[7]);
        ((uint4*)(Ml + ofs))[0] = make_uint4(lob[0], lob[1], lob[2], lob[3]);
        ((uint4*)(Ml + ofs))[1] = make_uint4(lob[4], lob[5], lob[6], lob[7]);
    }
    {
        float sc = cinv[v0 + row];
        unsigned hib[8], lob[8];
        #pragma unroll
        for (int j = 0; j < 8; j++) {
            unsigned short h0, l0, h1, l1;
            split_bf(T[cs + 2 * j][row] * sc, h0, l0);
            split_bf(T[cs + 2 * j + 1][row] * sc, h1, l1);
            hib[j] = (unsigned)h0 | ((unsigned)h1 << 16);
            lob[j] = (unsigned)l0 | ((unsigned)l1 << 16);
        }
        size_t ofs = (size_t)2048 * NN + (size_t)(v0 + row) * NN + w0 + cs;
        ((uint4*)(Mh + ofs))[0] = make_uint4(hib[0], hib[1], hib[2], hib[3]);
        ((uint4*)(Mh + ofs))[1] = make_uint4(hib[4], hib[5], hib[6], hib[7]);
        ((uint4*)(Ml + ofs))[0] = make_uint4(lob[0], lob[1], lob[2], lob[3]);
        ((uint4*)(Ml + ofs))[1] = make_uint4(lob[4], lob[5], lob[6], lob[7]);
    }
}

// ---------------- M rows (g) squared: rows g*2048 -> rows g*2048+1024 ----------------
__global__ __launch_bounds__(256) void k_msq(
        unsigned short* __restrict__ Mh, unsigned short* __restrict__ Ml) {
    int zz = blockIdx.z;
    size_t srcb = (size_t)zz * 2048 * NN;
    size_t dstb = srcb + (size_t)1024 * NN;
    int w0 = blockIdx.x * 64, n0 = blockIdx.y * 64;

    __shared__ unsigned short sAh[64 * APAD + 32];
    __shared__ unsigned short sAl[64 * APAD + 32];
    __shared__ unsigned short sBh[64 * APAD + 32];
    __shared__ unsigned short sBl[64 * APAD + 32];

    int tid = threadIdx.x;
    int lane = tid & 63, wave = tid >> 6;
    int wr = (wave >> 1) * 32, wc = (wave & 1) * 32;
    int l15 = lane & 15, quad = lane >> 4;
    int arow = tid >> 2, akk = (tid & 3) * 8;
    int bkr = tid & 31, bc8 = (tid >> 5) * 8;

    v4f acc[2][2];
    #pragma unroll
    for (int i = 0; i < 2; i++)
        #pragma unroll
        for (int j = 0; j < 2; j++) { acc[i][j][0]=0.f; acc[i][j][1]=0.f; acc[i][j][2]=0.f; acc[i][j][3]=0.f; }

    for (int k0 = 0; k0 < NN; k0 += 32) {
        size_t aofs = srcb + (size_t)(w0 + arow) * NN + k0 + akk;
        *(uint4*)&sAh[XC(arow, akk)] = *(const uint4*)(Mh + aofs);
        *(uint4*)&sAl[XC(arow, akk)] = *(const uint4*)(Ml + aofs);
        size_t bofs = srcb + (size_t)(k0 + bkr) * NN + n0 + bc8;
        uint4 bh = *(const uint4*)(Mh + bofs);
        uint4 bl = *(const uint4*)(Ml + bofs);
        const unsigned short* ph = (const unsigned short*)&bh;
        const unsigned short* pl = (const unsigned short*)&bl;
        #pragma unroll
        for (int j = 0; j < 8; j++) {
            sBh[XE(bc8 + j, bkr)] = ph[j];
            sBl[XE(bc8 + j, bkr)] = pl[j];
        }
        __syncthreads();

        v8s ah0 = *(const v8s*)&sAh[XC(wr + l15, quad * 8)];
        v8s ah1 = *(const v8s*)&sAh[XC(wr + 16 + l15, quad * 8)];
        v8s al0 = *(const v8s*)&sAl[XC(wr + l15, quad * 8)];
        v8s al1 = *(const v8s*)&sAl[XC(wr + 16 + l15, quad * 8)];
        #pragma unroll
        for (int j = 0; j < 2; j++) {
            v8s bh8 = *(const v8s*)&sBh[XC(wc + j * 16 + l15, quad * 8)];
            v8s bl8 = *(const v8s*)&sBl[XC(wc + j * 16 + l15, quad * 8)];
            acc[0][j] = __builtin_amdgcn_mfma_f32_16x16x32_bf16(ah0, bh8, acc[0][j], 0, 0, 0);
            acc[1][j] = __builtin_amdgcn_mfma_f32_16x16x32_bf16(ah1, bh8, acc[1][j], 0, 0, 0);
            acc[0][j] = __builtin_amdgcn_mfma_f32_16x16x32_bf16(ah0, bl8, acc[0][j], 0, 0, 0);
            acc[1][j] = __builtin_amdgcn_mfma_f32_16x16x32_bf16(ah1, bl8, acc[1][j], 0, 0, 0);
            acc[0][j] = __builtin_amdgcn_mfma_f32_16x16x32_bf16(al0, bh8, acc[0][j], 0, 0, 0);
            acc[1][j] = __builtin_amdgcn_mfma_f32_16x16x32_bf16(al1, bh8, acc[1][j], 0, 0, 0);
        }
        __syncthreads();
    }

    #pragma unroll
    for (int i = 0; i < 2; i++)
        #pragma unroll
        for (int j = 0; j < 2; j++) {
            int rb = w0 + wr + i * 16 + quad * 4;
            int cc = n0 + wc + j * 16 + l15;
            #pragma unroll
            for (int rr = 0; rr < 4; rr++) {
                unsigned short hi, lo;
                split_bf(acc[i][j][rr], hi, lo);
                size_t o = dstb + (size_t)(rb + rr) * NN + cc;
                Mh[o] = hi; Ml[o] = lo;
            }
        }
}

// ---------------- xh build: cols 0-63 = enc(x_t), 64-127 = h ----------------
__global__ void k_enc2(const float* __restrict__ x, const float* __restrict__ W_enc,
                       const float* __restrict__ b_enc, const float* __restrict__ emb,
                       const float* __restrict__ h, float* __restrict__ xh, int t) {
    size_t idx = (size_t)blockIdx.x * 256 + threadIdx.x;
    size_t row = idx >> 7; int c = (int)(idx & 127);
    if (c < HH) {
        int b = (int)(row >> 10), n = (int)(row & 1023);
        const float* xr = x + (((size_t)b * TT + t) * NN + n) * FF;
        float acc = b_enc[c] + emb[(size_t)n * HH + c];
        #pragma unroll
        for (int f = 0; f < FF; f++) acc += xr[f] * W_enc[f * HH + c];
        xh[idx] = acc;
    } else {
        xh[idx] = h[row * HH + (c - HH)];
    }
}

// ---------------- stacked hop: Y[n, g*gmul+off+yc] = (M @ X)[g*1024+n, yc] ----------------
__global__ __launch_bounds__(256) void k_hopS(
        const unsigned short* __restrict__ Mh, const unsigned short* __restrict__ Ml,
        const float* __restrict__ Xin, int in_stride, int in_off,
        float* __restrict__ Yout, int out_stride, int out_gmul, int out_off) {
    int rt = blockIdx.x;
    int g = rt >> 4;
    int n0 = (rt & 15) * 64;
    int b = blockIdx.z;
    const float* X = Xin + (size_t)b * NN * in_stride + in_off + blockIdx.y * 64;
    float* Y = Yout + (size_t)b * NN * out_stride + out_gmul * g + out_off + blockIdx.y * 64;
    size_t mbase = (size_t)rt * 64 * NN;

    __shared__ unsigned short sAh[64 * APAD + 32];
    __shared__ unsigned short sAl[64 * APAD + 32];
    __shared__ unsigned short sXh[64 * APAD + 32];
    __shared__ unsigned short sXl[64 * APAD + 32];

    int tid = threadIdx.x;
    int lane = tid & 63, wave = tid >> 6;
    int wr = (wave >> 1) * 32, wc = (wave & 1) * 32;
    int l15 = lane & 15, quad = lane >> 4;
    int arow = tid >> 2, akk = (tid & 3) * 8;
    int xkr = tid & 31, xc8 = (tid >> 5) * 8;

    v4f acc[2][2];
    #pragma unroll
    for (int i = 0; i < 2; i++)
        #pragma unroll
        for (int j = 0; j < 2; j++) { acc[i][j][0]=0.f; acc[i][j][1]=0.f; acc[i][j][2]=0.f; acc[i][j][3]=0.f; }

    for (int k0 = 0; k0 < NN; k0 += 32) {
        size_t aofs = mbase + (size_t)arow * NN + k0 + akk;
        *(uint4*)&sAh[XC(arow, akk)] = *(const uint4*)(Mh + aofs);
        *(uint4*)&sAl[XC(arow, akk)] = *(const uint4*)(Ml + aofs);
        const float* px = X + (size_t)(k0 + xkr) * in_stride + xc8;
        float4 x0 = *(const float4*)px;
        float4 x1 = *(const float4*)(px + 4);
        float xv[8] = {x0.x, x0.y, x0.z, x0.w, x1.x, x1.y, x1.z, x1.w};
        #pragma unroll
        for (int j = 0; j < 8; j++) {
            unsigned short hi, lo;
            split_bf(xv[j], hi, lo);
            sXh[XE(xc8 + j, xkr)] = hi;
            sXl[XE(xc8 + j, xkr)] = lo;
        }
        __syncthreads();

        v8s ah0 = *(const v8s*)&sAh[XC(wr + l15, quad * 8)];
        v8s ah1 = *(const v8s*)&sAh[XC(wr + 16 + l15, quad * 8)];
        v8s al0 = *(const v8s*)&sAl[XC(wr + l15, quad * 8)];
        v8s al1 = *(const v8s*)&sAl[XC(wr + 16 + l15, quad * 8)];
        #pragma unroll
        for (int j = 0; j < 2; j++) {
            v8s bh = *(const v8s*)&sXh[XC(wc + j * 16 + l15, quad * 8)];
            v8s bl = *(const v8s*)&sXl[XC(wc + j * 16 + l15, quad * 8)];
            acc[0][j] = __builtin_amdgcn_mfma_f32_16x16x32_bf16(ah0, bh, acc[0][j], 0, 0, 0);
            acc[1][j] = __builtin_amdgcn_mfma_f32_16x16x32_bf16(ah1, bh, acc[1][j], 0, 0, 0);
            acc[0][j] = __builtin_amdgcn_mfma_f32_16x16x32_bf16(ah0, bl, acc[0][j], 0, 0, 0);
            acc[1][j] = __builtin_amdgcn_mfma_f32_16x16x32_bf16(ah1, bl, acc[1][j], 0, 0, 0);
            acc[0][j] = __builtin_amdgcn_mfma_f32_16x16x32_bf16(al0, bh, acc[0][j], 0, 0, 0);
            acc[1][j] = __builtin_amdgcn_mfma_f32_16x16x32_bf16(al1, bh, acc[1][j], 0, 0, 0);
        }
        __syncthreads();
    }

    #pragma unroll
    for (int i = 0; i < 2; i++)
        #pragma unroll
        for (int j = 0; j < 2; j++) {
            int rbase = n0 + wr + i * 16 + quad * 4;
            int cc = wc + j * 16 + l15;
            #pragma unroll
            for (int rr = 0; rr < 4; rr++)
                Y[(size_t)(rbase + rr) * out_stride + cc] = acc[i][j][rr];
        }
}

// ---------------- merged gates: r,u = sigmoid(feats@W+b); rh->xh[64..127], u->xh[0..63] ----------------
__global__ __launch_bounds__(256) void k_gates(
        const float* __restrict__ feats,
        const float* __restrict__ W_r, const float* __restrict__ W_u,
        const float* __restrict__ b_r, const float* __restrict__ b_u,
        const float* __restrict__ h, float* __restrict__ xh) {
    int row0 = blockIdx.x * 32;
    __shared__ float Fa[16][36];
    __shared__ float Wr[16][68];
    __shared__ float Wu[16][68];

    int tid = threadIdx.x;
    int ar = tid >> 3,  ak2 = (tid & 7) * 2;
    int bk = tid >> 4,  bc4 = (tid & 15) * 4;
    int ty = tid >> 4,  tx  = tid & 15;

    float accr[2][4] = {}, accu[2][4] = {};
    for (int k0 = 0; k0 < FS; k0 += 16) {
        float2 fv = *(const float2*)(feats + (size_t)(row0 + ar) * FS + k0 + ak2);
        Fa[ak2 + 0][ar] = fv.x; Fa[ak2 + 1][ar] = fv.y;
        *(float4*)&Wr[bk][bc4] = *(const float4*)(W_r + (size_t)(k0 + bk) * HH + bc4);
        *(float4*)&Wu[bk][bc4] = *(const float4*)(W_u + (size_t)(k0 + bk) * HH + bc4);
        __syncthreads();
        #pragma unroll
        for (int kk = 0; kk < 16; kk++) {
            float a0 = Fa[kk][ty * 2 + 0];
            float a1 = Fa[kk][ty * 2 + 1];
            const float4 r4 = *(const float4*)&Wr[kk][tx * 4];
            const float4 u4 = *(const float4*)&Wu[kk][tx * 4];
            accr[0][0] += a0 * r4.x; accr[0][1] += a0 * r4.y; accr[0][2] += a0 * r4.z; accr[0][3] += a0 * r4.w;
            accr[1][0] += a1 * r4.x; accr[1][1] += a1 * r4.y; accr[1][2] += a1 * r4.z; accr[1][3] += a1 * r4.w;
            accu[0][0] += a0 * u4.x; accu[0][1] += a0 * u4.y; accu[0][2] += a0 * u4.z; accu[0][3] += a0 * u4.w;
            accu[1][0] += a1 * u4.x; accu[1][1] += a1 * u4.y; accu[1][2] += a1 * u4.z; accu[1][3] += a1 * u4.w;
        }
        __syncthreads();
    }
    #pragma unroll
    for (int i = 0; i < 2; i++) {
        size_t row = row0 + ty * 2 + i;
        #pragma unroll
        for (int j = 0; j < 4; j++) {
            int c = tx * 4 + j;
            float r = 1.f / (1.f + expf(-(accr[i][j] + b_r[c])));
            float u = 1.f / (1.f + expf(-(accu[i][j] + b_u[c])));
            xh[row * 128 + 64 + c] = r * h[row * HH + c];   // rh
            xh[row * 128 + c] = u;                          // u (x-cols dead)
        }
    }
}

// ---------------- candidate + h update ----------------
__global__ __launch_bounds__(256) void k_cand(
        const float* __restrict__ feats, const float* __restrict__ W_c,
        const float* __restrict__ b_c, const float* __restrict__ xh,
        float* __restrict__ h) {
    int row0 = blockIdx.x * 32;
    __shared__ float Fa[16][36];
    __shared__ float Wb[16][68];

    int tid = threadIdx.x;
    int ar = tid >> 3,  ak2 = (tid & 7) * 2;
    int bk = tid >> 4,  bc4 = (tid & 15) * 4;
    int ty = tid >> 4,  tx  = tid & 15;

    float acc[2][4] = {};
    for (int k0 = 0; k0 < FS; k0 += 16) {
        float2 fv = *(const float2*)(feats + (size_t)(row0 + ar) * FS + k0 + ak2);
        Fa[ak2 + 0][ar] = fv.x; Fa[ak2 + 1][ar] = fv.y;
        *(float4*)&Wb[bk][bc4] = *(const float4*)(W_c + (size_t)(k0 + bk) * HH + bc4);
        __syncthreads();
        #pragma unroll
        for (int kk = 0; kk < 16; kk++) {
            float a0 = Fa[kk][ty * 2 + 0];
            float a1 = Fa[kk][ty * 2 + 1];
            const float4 b4 = *(const float4*)&Wb[kk][tx * 4];
            acc[0][0] += a0 * b4.x; acc[0][1] += a0 * b4.y; acc[0][2] += a0 * b4.z; acc[0][3] += a0 * b4.w;
            acc[1][0] += a1 * b4.x; acc[1][1] += a1 * b4.y; acc[1][2] += a1 * b4.z; acc[1][3] += a1 * b4.w;
        }
        __syncthreads();
    }
    #pragma unroll
    for (int i = 0; i < 2; i++) {
        size_t row = row0 + ty * 2 + i;
        #pragma unroll
        for (int j = 0; j < 4; j++) {
            int c = tx * 4 + j;
            float cv = tanhf(acc[i][j] + b_c[c]);
            float u = xh[row * 128 + c];
            float hv = h[row * HH + c];
            h[row * HH + c] = u * hv + (1.f - u) * cv;
        }
    }
}

// ---------------- DiffConv operator build ----------------
__global__ void k_deg(const int* __restrict__ ei32, const float* __restrict__ ew,
                      float* __restrict__ degd, float* __restrict__ degs) {
    int e = blockIdx.x * 256 + threadIdx.x;
    float w = ew[e];
    atomicAdd(&degd[ei32[EE + e]], w);
    atomicAdd(&degs[ei32[e]], w);
}
__global__ void k_spadd(const int* __restrict__ ei32, const float* __restrict__ ew,
                        const float* __restrict__ degd, const float* __restrict__ degs,
                        float* __restrict__ temp) {
    int e = blockIdx.x * 256 + threadIdx.x;
    int s = ei32[e], d = ei32[EE + e];
    float w = ew[e];
    float dd = degd[d], ds = degs[s];
    float wfv = dd > 0.f ? w / dd : 0.f;
    float wbv = ds > 0.f ? w / ds : 0.f;
    atomicAdd(&temp[(size_t)d * NN + s], wfv);
    atomicAdd(&temp[(size_t)NN * NN + (size_t)s * NN + d], wbv);
}
// temp[0] -> M rows 0..1023 (Sf), temp[1] -> M rows 2048..3071 (Sb)
__global__ void k_spconv(const float* __restrict__ temp,
                         unsigned short* __restrict__ Mh, unsigned short* __restrict__ Ml) {
    size_t i0 = ((size_t)blockIdx.x * 256 + threadIdx.x) * 8;
    size_t dst = (i0 < (size_t)NN * NN) ? i0 : i0 + (size_t)NN * NN;
    unsigned short h8[8], l8[8];
    #pragma unroll
    for (int j = 0; j < 8; j++) split_bf(temp[i0 + j], h8[j], l8[j]);
    *(uint4*)(Mh + dst) = *(uint4*)h8;
    *(uint4*)(Ml + dst) = *(uint4*)l8;
}

__global__ void k_featd_h(const float* __restrict__ h, float* __restrict__ featd) {
    size_t idx = (size_t)blockIdx.x * 256 + threadIdx.x;
    size_t row = idx >> 6; int c = (int)(idx & 63);
    featd[row * DIN + c] = h[idx];
}

__global__ __launch_bounds__(256) void k_z(
        const float* __restrict__ featd, const float* __restrict__ W_diff,
        const float* __restrict__ b_diff, float* __restrict__ z) {
    int row0 = blockIdx.x * 4;
    __shared__ float sF[4 * DIN];
    int tid = threadIdx.x;
    for (int i = tid; i < 4 * DIN / 4; i += 256)
        *(float4*)&sF[i * 4] = *(const float4*)&featd[(size_t)row0 * DIN + (size_t)i * 4];
    __syncthreads();
    int lr = tid >> 6, ch = tid & 63;
    const float* f = &sF[lr * DIN];
    float acc = b_diff[ch];
    for (int k = 0; k < DIN; k++) acc += f[k] * W_diff[k * HH + ch];
    z[(size_t)(row0 + lr) * HH + ch] = acc;
}

__global__ void k_dec(const float* __restrict__ z, const float* __restrict__ W_dec,
                      const float* __restrict__ b_dec, float* __restrict__ out) {
    size_t idx = (size_t)blockIdx.x * 256 + threadIdx.x;
    size_t row = idx / ODIM; int o = (int)(idx % ODIM);
    const float* zr = z + row * HH;
    float acc = b_dec[o];
    for (int k = 0; k < HH; k++) acc += zr[k] * W_dec[k * ODIM + o];
    int b = (int)(row >> 10), n = (int)(row & 1023);
    int t = o >> 3, f = o & 7;
    out[(((size_t)b * TT + t) * NN + n) * FF + f] = acc;
}

extern "C" void kernel_launch(void* const* d_in, const int* in_sizes, int n_in,
                              void* d_out, int out_size, void* d_ws, size_t ws_size,
                              hipStream_t stream) {
    const float* x      = (const float*)d_in[0];
    const int*   eiraw  = (const int*)  d_in[1];
    const float* ew     = (const float*)d_in[2];
    const float* adj    = (const float*)d_in[3];
    const float* W_enc  = (const float*)d_in[4];
    const float* b_enc  = (const float*)d_in[5];
    const float* emb    = (const float*)d_in[6];
    const float* W_r    = (const float*)d_in[7];
    const float* b_r    = (const float*)d_in[8];
    const float* W_u    = (const float*)d_in[9];
    const float* b_u    = (const float*)d_in[10];
    const float* W_c    = (const float*)d_in[11];
    const float* b_c    = (const float*)d_in[12];
    const float* W_diff = (const float*)d_in[13];
    const float* b_diff = (const float*)d_in[14];
    const float* W_dec  = (const float*)d_in[15];
    const float* b_dec  = (const float*)d_in[16];

    // ---- workspace: 60.0 MiB total ----
    unsigned short* Mh = (unsigned short*)d_ws;          // [4096][1024] bf16 hi (8 MiB)
    unsigned short* Ml = Mh + (size_t)4096 * NN;         // lo (8 MiB)
    float* xh    = (float*)(Ml + (size_t)4096 * NN);     // B*N*128  (8 MiB)
    float* feats = xh + (size_t)BB * NN * 128;           // B*N*512  (32 MiB)
    float* h     = feats + (size_t)BB * NN * FS;         // B*N*64   (4 MiB)
    // overlays
    float* rinv  = feats;              // pre-loop only
    float* cinv  = feats + NN;
    int*   eifl  = (int*)(xh + (size_t)1216 * 1024);     // readout only (xh x-cols dead)
    int*   ei32  = (int*)(xh + (size_t)1280 * 1024);
    float* degd  = xh + (size_t)1536 * 1024;
    float* degs  = degd + NN;
    float* sptmp = feats + (size_t)5 * 1024 * 1024;      // feats+20MiB, 8 MiB
    float* featd = feats;                                // B*N*320 (20 MiB)
    float* z     = xh;                                   // B*N*64 (4 MiB)

    hipMemsetAsync(h, 0, (size_t)BB * NN * HH * 4, stream);

    // ---- build M = [Af; Af^2; Ab; Ab^2] ----
    k_rowsum<<<NN, 256, 0, stream>>>(adj, rinv);
    k_colsum<<<NN / 256, 256, 0, stream>>>(adj, cinv);
    k_prepA<<<dim3(16, 16), 256, 0, stream>>>(adj, rinv, cinv, Mh, Ml);
    k_msq<<<dim3(16, 16, 2), 256, 0, stream>>>(Mh, Ml);

    for (int t = 0; t < TT; t++) {
        k_enc2<<<BB * NN * 128 / 256, 256, 0, stream>>>(x, W_enc, b_enc, emb, h, xh, t);
        // all 4 operators x [x|h] in one launch -> feats cols g*128 + 0..127
        k_hopS<<<dim3(64, 2, 16), 256, 0, stream>>>(Mh, Ml, xh, 128, 0, feats, FS, 128, 0);
        // gates r+u; rh -> xh[64..127], u -> xh[0..63]
        k_gates<<<BB * NN / 32, 256, 0, stream>>>(feats, W_r, W_u, b_r, b_u, h, xh);
        // all 4 operators @ rh in one launch -> overwrite feats h-cols g*128 + 64..127
        k_hopS<<<dim3(64, 1, 16), 256, 0, stream>>>(Mh, Ml, xh, 128, 64, feats, FS, 128, 64);
        k_cand<<<BB * NN / 32, 256, 0, stream>>>(feats, W_c, b_c, xh, h);
    }

    // ---- DiffConv readout ----
    k_ei_detect<<<1, 256, 0, stream>>>(eiraw, eifl);
    k_ei_norm<<<2 * EE / 256, 256, 0, stream>>>(eiraw, eifl, ei32);
    hipMemsetAsync(degd, 0, (size_t)2 * NN * 4, stream);
    hipMemsetAsync(sptmp, 0, (size_t)2 * NN * NN * 4, stream);
    k_deg<<<EE / 256, 256, 0, stream>>>(ei32, ew, degd, degs);
    k_spadd<<<EE / 256, 256, 0, stream>>>(ei32, ew, degd, degs, sptmp);
    k_spconv<<<2 * NN * NN / (256 * 8), 256, 0, stream>>>(sptmp, Mh, Ml);  // SP rows g0,g2
    k_msq<<<dim3(16, 16, 2), 256, 0, stream>>>(Mh, Ml);                    // SP^2 rows g1,g3
    k_featd_h<<<BB * NN * HH / 256, 256, 0, stream>>>(h, featd);
    // [Sf;Sf2;Sb;Sb2] @ h -> featd cols 64 + g*64
    k_hopS<<<dim3(64, 1, 16), 256, 0, stream>>>(Mh, Ml, h, 64, 0, featd, DIN, 64, 64);
    k_z<<<BB * NN / 4, 256, 0, stream>>>(featd, W_diff, b_diff, z);
    k_dec<<<(BB * NN * ODIM) / 256, 256, 0, stream>>>(z, W_dec, b_dec, (float*)d_out);
}

// Round 13
// 2775.687 us; speedup vs baseline: 7.1983x; 1.0849x over previous
//
#include <hip/hip_runtime.h>
#include <hip/hip_bf16.h>
#include <math.h>

#define BB 16
#define TT 12
#define NN 1024
#define FF 8
#define HH 64
#define EE 32768
#define DIN 320   // H * (2K+1)
#define ODIM 96   // F * HORIZON
#define FS 512    // feats cols: [Af|Af2|Ab|Ab2] x [x(64)|h(64)]
#define APAD 40   // plain row stride (ushort): <=2-way bank aliasing (free)

typedef short v8s __attribute__((ext_vector_type(8)));
typedef float v4f __attribute__((ext_vector_type(4)));

__device__ __forceinline__ unsigned short f2bf_rne(float v) {
    unsigned u = __float_as_uint(v);
    u += 0x7FFF + ((u >> 16) & 1);
    return (unsigned short)(u >> 16);
}
__device__ __forceinline__ float bfu2f(unsigned short u) {
    return __uint_as_float((unsigned)u << 16);
}
__device__ __forceinline__ void split_bf(float v, unsigned short& hi, unsigned short& lo) {
    hi = f2bf_rne(v);
    lo = f2bf_rne(v - bfu2f(hi));
}

// ---------------- edge_index insurance ----------------
__global__ void k_ei_detect(const int* __restrict__ ei_raw, int* __restrict__ flag) {
    __shared__ int s[256];
    s[threadIdx.x] = ei_raw[2 * threadIdx.x + 1];
    __syncthreads();
    for (int st = 128; st > 0; st >>= 1) {
        if (threadIdx.x < st) s[threadIdx.x] |= s[threadIdx.x + st];
        __syncthreads();
    }
    if (threadIdx.x == 0) flag[0] = (s[0] == 0) ? 1 : 0;
}
__global__ void k_ei_norm(const int* __restrict__ ei_raw, const int* __restrict__ flag,
                          int* __restrict__ ei32) {
    int j = blockIdx.x * 256 + threadIdx.x;
    ei32[j] = flag[0] ? ei_raw[2 * j] : ei_raw[j];
}

// ---------------- support normalization ----------------
__global__ void k_rowsum(const float* __restrict__ adj, float* __restrict__ rinv) {
    __shared__ float s[256];
    int i = blockIdx.x;
    float acc = 0.f;
    for (int j = threadIdx.x; j < NN; j += 256) acc += adj[i * NN + j];
    s[threadIdx.x] = acc;
    __syncthreads();
    for (int st = 128; st > 0; st >>= 1) {
        if (threadIdx.x < st) s[threadIdx.x] += s[threadIdx.x + st];
        __syncthreads();
    }
    if (threadIdx.x == 0) rinv[i] = (s[0] != 0.f) ? 1.f / s[0] : 0.f;
}
__global__ void k_colsum(const float* __restrict__ adj, float* __restrict__ cinv) {
    int j = blockIdx.x * 256 + threadIdx.x;
    float acc = 0.f;
    for (int i = 0; i < NN; i++) acc += adj[i * NN + j];
    cinv[j] = (acc != 0.f) ? 1.f / acc : 0.f;
}

// ---------------- Af -> M rows 0..1023, Ab -> M rows 2048..3071 (split bf16) ----------------
__global__ __launch_bounds__(256) void k_prepA(
        const float* __restrict__ adj, const float* __restrict__ rinv,
        const float* __restrict__ cinv,
        unsigned short* __restrict__ Mh, unsigned short* __restrict__ Ml) {
    int w0 = blockIdx.x * 64, v0 = blockIdx.y * 64;
    __shared__ float T[64][68];
    int row = threadIdx.x >> 2, cs = (threadIdx.x & 3) * 16;
    #pragma unroll
    for (int j = 0; j < 4; j++)
        *(float4*)&T[row][cs + j * 4] = *(const float4*)(adj + (size_t)(w0 + row) * NN + v0 + cs + j * 4);
    __syncthreads();
    {
        float sc = rinv[w0 + row];
        unsigned short h8[16], l8[16];
        #pragma unroll
        for (int j = 0; j < 16; j++) split_bf(T[row][cs + j] * sc, h8[j], l8[j]);
        size_t ofs = (size_t)(w0 + row) * NN + v0 + cs;
        ((uint4*)(Mh + ofs))[0] = *(uint4*)&h8[0];
        ((uint4*)(Mh + ofs))[1] = *(uint4*)&h8[8];
        ((uint4*)(Ml + ofs))[0] = *(uint4*)&l8[0];
        ((uint4*)(Ml + ofs))[1] = *(uint4*)&l8[8];
    }
    {
        float sc = cinv[v0 + row];
        unsigned short h8[16], l8[16];
        #pragma unroll
        for (int j = 0; j < 16; j++) split_bf(T[cs + j][row] * sc, h8[j], l8[j]);
        size_t ofs = (size_t)2048 * NN + (size_t)(v0 + row) * NN + w0 + cs;
        ((uint4*)(Mh + ofs))[0] = *(uint4*)&h8[0];
        ((uint4*)(Mh + ofs))[1] = *(uint4*)&h8[8];
        ((uint4*)(Ml + ofs))[0] = *(uint4*)&l8[0];
        ((uint4*)(Ml + ofs))[1] = *(uint4*)&l8[8];
    }
}

// ---------------- M rows (g) squared: rows g*2048 -> g*2048+1024 ----------------
__global__ __launch_bounds__(256) void k_msq(
        unsigned short* __restrict__ Mh, unsigned short* __restrict__ Ml) {
    int zz = blockIdx.z;
    size_t srcb = (size_t)zz * 2048 * NN;
    size_t dstb = srcb + (size_t)1024 * NN;
    int w0 = blockIdx.x * 64, n0 = blockIdx.y * 64;

    __shared__ unsigned short sAh[64 * APAD];
    __shared__ unsigned short sAl[64 * APAD];
    __shared__ unsigned short sBh[64 * APAD];
    __shared__ unsigned short sBl[64 * APAD];

    int tid = threadIdx.x;
    int lane = tid & 63, wave = tid >> 6;
    int wr = (wave >> 1) * 32, wc = (wave & 1) * 32;
    int l15 = lane & 15, quad = lane >> 4;
    int arow = tid >> 2, akk = (tid & 3) * 8;
    int bkr = tid & 31, bc8 = (tid >> 5) * 8;

    v4f acc[2][2];
    #pragma unroll
    for (int i = 0; i < 2; i++)
        #pragma unroll
        for (int j = 0; j < 2; j++) { acc[i][j][0]=0.f; acc[i][j][1]=0.f; acc[i][j][2]=0.f; acc[i][j][3]=0.f; }

    for (int k0 = 0; k0 < NN; k0 += 32) {
        size_t aofs = srcb + (size_t)(w0 + arow) * NN + k0 + akk;
        *(uint4*)&sAh[arow * APAD + akk] = *(const uint4*)(Mh + aofs);
        *(uint4*)&sAl[arow * APAD + akk] = *(const uint4*)(Ml + aofs);
        size_t bofs = srcb + (size_t)(k0 + bkr) * NN + n0 + bc8;
        uint4 bh = *(const uint4*)(Mh + bofs);
        uint4 bl = *(const uint4*)(Ml + bofs);
        const unsigned short* ph = (const unsigned short*)&bh;
        const unsigned short* pl = (const unsigned short*)&bl;
        #pragma unroll
        for (int j = 0; j < 8; j++) {
            sBh[(bc8 + j) * APAD + bkr] = ph[j];
            sBl[(bc8 + j) * APAD + bkr] = pl[j];
        }
        __syncthreads();

        v8s ah0 = *(const v8s*)&sAh[(wr + l15) * APAD + quad * 8];
        v8s ah1 = *(const v8s*)&sAh[(wr + 16 + l15) * APAD + quad * 8];
        v8s al0 = *(const v8s*)&sAl[(wr + l15) * APAD + quad * 8];
        v8s al1 = *(const v8s*)&sAl[(wr + 16 + l15) * APAD + quad * 8];
        #pragma unroll
        for (int j = 0; j < 2; j++) {
            v8s bh8 = *(const v8s*)&sBh[(wc + j * 16 + l15) * APAD + quad * 8];
            v8s bl8 = *(const v8s*)&sBl[(wc + j * 16 + l15) * APAD + quad * 8];
            acc[0][j] = __builtin_amdgcn_mfma_f32_16x16x32_bf16(ah0, bh8, acc[0][j], 0, 0, 0);
            acc[1][j] = __builtin_amdgcn_mfma_f32_16x16x32_bf16(ah1, bh8, acc[1][j], 0, 0, 0);
            acc[0][j] = __builtin_amdgcn_mfma_f32_16x16x32_bf16(ah0, bl8, acc[0][j], 0, 0, 0);
            acc[1][j] = __builtin_amdgcn_mfma_f32_16x16x32_bf16(ah1, bl8, acc[1][j], 0, 0, 0);
            acc[0][j] = __builtin_amdgcn_mfma_f32_16x16x32_bf16(al0, bh8, acc[0][j], 0, 0, 0);
            acc[1][j] = __builtin_amdgcn_mfma_f32_16x16x32_bf16(al1, bh8, acc[1][j], 0, 0, 0);
        }
        __syncthreads();
    }

    #pragma unroll
    for (int i = 0; i < 2; i++)
        #pragma unroll
        for (int j = 0; j < 2; j++) {
            int rb = w0 + wr + i * 16 + quad * 4;
            int cc = n0 + wc + j * 16 + l15;
            #pragma unroll
            for (int rr = 0; rr < 4; rr++) {
                unsigned short hi, lo;
                split_bf(acc[i][j][rr], hi, lo);
                size_t o = dstb + (size_t)(rb + rr) * NN + cc;
                Mh[o] = hi; Ml[o] = lo;
            }
        }
}

// ---------------- encoder -> XT x-cols (transposed split): XT[b][c][n] ----------------
__global__ void k_encT(const float* __restrict__ x, const float* __restrict__ W_enc,
                       const float* __restrict__ b_enc, const float* __restrict__ emb,
                       unsigned short* __restrict__ XTh, unsigned short* __restrict__ XTl, int t) {
    int b = blockIdx.x >> 6;        // 1024 blocks: b*64 + c
    int c = blockIdx.x & 63;
    int n8 = threadIdx.x * 8;       // 128 threads x 8 n
    float w[FF];
    #pragma unroll
    for (int f = 0; f < FF; f++) w[f] = W_enc[f * HH + c];
    float be = b_enc[c];
    unsigned short h8[8], l8[8];
    #pragma unroll
    for (int j = 0; j < 8; j++) {
        int n = n8 + j;
        const float* xr = x + (((size_t)b * TT + t) * NN + n) * FF;
        float acc = be + emb[(size_t)n * HH + c];
        #pragma unroll
        for (int f = 0; f < FF; f++) acc += xr[f] * w[f];
        split_bf(acc, h8[j], l8[j]);
    }
    size_t o = ((size_t)b * 128 + c) * NN + n8;
    *(uint4*)(XTh + o) = *(uint4*)h8;
    *(uint4*)(XTl + o) = *(uint4*)l8;
}

// ---------------- stacked hop, both operands pre-split: Y = (M @ XT^T)[g-block] ----------------
// grid (64 = 4g x 16 ntiles, ncol64, 16 b)
__global__ __launch_bounds__(256) void k_hopS2(
        const unsigned short* __restrict__ Mh, const unsigned short* __restrict__ Ml,
        const unsigned short* __restrict__ XTh, const unsigned short* __restrict__ XTl,
        int in_off,
        float* __restrict__ Yout, int out_stride, int out_gmul, int out_off) {
    int rt = blockIdx.x;
    int g = rt >> 4;
    int n0 = (rt & 15) * 64;
    int b = blockIdx.z;
    int c0 = in_off + blockIdx.y * 64;
    const unsigned short* Xh = XTh + ((size_t)b * 128 + c0) * NN;
    const unsigned short* Xl = XTl + ((size_t)b * 128 + c0) * NN;
    float* Y = Yout + (size_t)b * NN * out_stride + out_gmul * g + out_off + blockIdx.y * 64;
    size_t mbase = (size_t)rt * 64 * NN;

    __shared__ unsigned short sAh[64 * APAD];
    __shared__ unsigned short sAl[64 * APAD];
    __shared__ unsigned short sXh[64 * APAD];
    __shared__ unsigned short sXl[64 * APAD];

    int tid = threadIdx.x;
    int lane = tid & 63, wave = tid >> 6;
    int wr = (wave >> 1) * 32, wc = (wave & 1) * 32;
    int l15 = lane & 15, quad = lane >> 4;
    int arow = tid >> 2, akk = (tid & 3) * 8;

    v4f acc[2][2];
    #pragma unroll
    for (int i = 0; i < 2; i++)
        #pragma unroll
        for (int j = 0; j < 2; j++) { acc[i][j][0]=0.f; acc[i][j][1]=0.f; acc[i][j][2]=0.f; acc[i][j][3]=0.f; }

    for (int k0 = 0; k0 < NN; k0 += 32) {
        size_t aofs = mbase + (size_t)arow * NN + k0 + akk;
        *(uint4*)&sAh[arow * APAD + akk] = *(const uint4*)(Mh + aofs);
        *(uint4*)&sAl[arow * APAD + akk] = *(const uint4*)(Ml + aofs);
        size_t xofs = (size_t)arow * NN + k0 + akk;
        *(uint4*)&sXh[arow * APAD + akk] = *(const uint4*)(Xh + xofs);
        *(uint4*)&sXl[arow * APAD + akk] = *(const uint4*)(Xl + xofs);
        __syncthreads();

        v8s ah0 = *(const v8s*)&sAh[(wr + l15) * APAD + quad * 8];
        v8s ah1 = *(const v8s*)&sAh[(wr + 16 + l15) * APAD + quad * 8];
        v8s al0 = *(const v8s*)&sAl[(wr + l15) * APAD + quad * 8];
        v8s al1 = *(const v8s*)&sAl[(wr + 16 + l15) * APAD + quad * 8];
        #pragma unroll
        for (int j = 0; j < 2; j++) {
            v8s bh = *(const v8s*)&sXh[(wc + j * 16 + l15) * APAD + quad * 8];
            v8s bl = *(const v8s*)&sXl[(wc + j * 16 + l15) * APAD + quad * 8];
            acc[0][j] = __builtin_amdgcn_mfma_f32_16x16x32_bf16(ah0, bh, acc[0][j], 0, 0, 0);
            acc[1][j] = __builtin_amdgcn_mfma_f32_16x16x32_bf16(ah1, bh, acc[1][j], 0, 0, 0);
            acc[0][j] = __builtin_amdgcn_mfma_f32_16x16x32_bf16(ah0, bl, acc[0][j], 0, 0, 0);
            acc[1][j] = __builtin_amdgcn_mfma_f32_16x16x32_bf16(ah1, bl, acc[1][j], 0, 0, 0);
            acc[0][j] = __builtin_amdgcn_mfma_f32_16x16x32_bf16(al0, bh, acc[0][j], 0, 0, 0);
            acc[1][j] = __builtin_amdgcn_mfma_f32_16x16x32_bf16(al1, bh, acc[1][j], 0, 0, 0);
        }
        __syncthreads();
    }

    #pragma unroll
    for (int i = 0; i < 2; i++)
        #pragma unroll
        for (int j = 0; j < 2; j++) {
            int rbase = n0 + wr + i * 16 + quad * 4;
            int cc = wc + j * 16 + l15;
            #pragma unroll
            for (int rr = 0; rr < 4; rr++)
                Y[(size_t)(rbase + rr) * out_stride + cc] = acc[i][j][rr];
        }
}

// ---------------- gates: r,u = sigmoid(feats@W+b); rh -> XT h-cols, u -> XT x-cols ----------------
__global__ __launch_bounds__(256) void k_gates(
        const float* __restrict__ feats,
        const float* __restrict__ W_r, const float* __restrict__ W_u,
        const float* __restrict__ b_r, const float* __restrict__ b_u,
        const float* __restrict__ h,
        unsigned short* __restrict__ XTh, unsigned short* __restrict__ XTl) {
    int row0 = blockIdx.x * 32;
    int b = row0 >> 10, n0g = row0 & 1023;
    __shared__ float Fa[16][36];
    __shared__ float Wr[16][68];
    __shared__ float Wu[16][68];
    __shared__ float sTr[64][33];
    __shared__ float sTu[64][33];

    int tid = threadIdx.x;
    int ar = tid >> 3,  ak2 = (tid & 7) * 2;
    int bk = tid >> 4,  bc4 = (tid & 15) * 4;
    int ty = tid >> 4,  tx  = tid & 15;

    float accr[2][4] = {}, accu[2][4] = {};
    for (int k0 = 0; k0 < FS; k0 += 16) {
        float2 fv = *(const float2*)(feats + (size_t)(row0 + ar) * FS + k0 + ak2);
        Fa[ak2 + 0][ar] = fv.x; Fa[ak2 + 1][ar] = fv.y;
        *(float4*)&Wr[bk][bc4] = *(const float4*)(W_r + (size_t)(k0 + bk) * HH + bc4);
        *(float4*)&Wu[bk][bc4] = *(const float4*)(W_u + (size_t)(k0 + bk) * HH + bc4);
        __syncthreads();
        #pragma unroll
        for (int kk = 0; kk < 16; kk++) {
            float a0 = Fa[kk][ty * 2 + 0];
            float a1 = Fa[kk][ty * 2 + 1];
            const float4 r4 = *(const float4*)&Wr[kk][tx * 4];
            const float4 u4 = *(const float4*)&Wu[kk][tx * 4];
            accr[0][0] += a0 * r4.x; accr[0][1] += a0 * r4.y; accr[0][2] += a0 * r4.z; accr[0][3] += a0 * r4.w;
            accr[1][0] += a1 * r4.x; accr[1][1] += a1 * r4.y; accr[1][2] += a1 * r4.z; accr[1][3] += a1 * r4.w;
            accu[0][0] += a0 * u4.x; accu[0][1] += a0 * u4.y; accu[0][2] += a0 * u4.z; accu[0][3] += a0 * u4.w;
            accu[1][0] += a1 * u4.x; accu[1][1] += a1 * u4.y; accu[1][2] += a1 * u4.z; accu[1][3] += a1 * u4.w;
        }
        __syncthreads();
    }
    #pragma unroll
    for (int i = 0; i < 2; i++) {
        int nloc = ty * 2 + i;
        size_t row = row0 + nloc;
        #pragma unroll
        for (int j = 0; j < 4; j++) {
            int c = tx * 4 + j;
            float r = 1.f / (1.f + expf(-(accr[i][j] + b_r[c])));
            float u = 1.f / (1.f + expf(-(accu[i][j] + b_u[c])));
            sTr[c][nloc] = r * h[row * HH + c];
            sTu[c][nloc] = u;
        }
    }
    __syncthreads();
    int c2 = tid >> 2, n8 = (tid & 3) * 8;
    unsigned short rh8[8], rl8[8], uh8[8], ul8[8];
    #pragma unroll
    for (int j = 0; j < 8; j++) {
        split_bf(sTr[c2][n8 + j], rh8[j], rl8[j]);
        split_bf(sTu[c2][n8 + j], uh8[j], ul8[j]);
    }
    size_t oh = ((size_t)b * 128 + 64 + c2) * NN + n0g + n8;   // rh -> h-cols
    size_t ou = ((size_t)b * 128 + c2) * NN + n0g + n8;        // u  -> x-cols (dead)
    *(uint4*)(XTh + oh) = *(uint4*)rh8;
    *(uint4*)(XTl + oh) = *(uint4*)rl8;
    *(uint4*)(XTh + ou) = *(uint4*)uh8;
    *(uint4*)(XTl + ou) = *(uint4*)ul8;
}

// ---------------- candidate + h update; new h -> h f32 AND XT h-cols ----------------
__global__ __launch_bounds__(256) void k_cand(
        const float* __restrict__ feats, const float* __restrict__ W_c,
        const float* __restrict__ b_c,
        const unsigned short* __restrict__ XTh, const unsigned short* __restrict__ XTl,
        float* __restrict__ h,
        unsigned short* __restrict__ XTho, unsigned short* __restrict__ XTlo) {
    int row0 = blockIdx.x * 32;
    int b = row0 >> 10, n0g = row0 & 1023;
    __shared__ float Fa[16][36];
    __shared__ float Wb[16][68];
    __shared__ float sT[64][33];

    int tid = threadIdx.x;
    int ar = tid >> 3,  ak2 = (tid & 7) * 2;
    int bk = tid >> 4,  bc4 = (tid & 15) * 4;
    int ty = tid >> 4,  tx  = tid & 15;

    float acc[2][4] = {};
    for (int k0 = 0; k0 < FS; k0 += 16) {
        float2 fv = *(const float2*)(feats + (size_t)(row0 + ar) * FS + k0 + ak2);
        Fa[ak2 + 0][ar] = fv.x; Fa[ak2 + 1][ar] = fv.y;
        *(float4*)&Wb[bk][bc4] = *(const float4*)(W_c + (size_t)(k0 + bk) * HH + bc4);
        __syncthreads();
        #pragma unroll
        for (int kk = 0; kk < 16; kk++) {
            float a0 = Fa[kk][ty * 2 + 0];
            float a1 = Fa[kk][ty * 2 + 1];
            const float4 b4 = *(const float4*)&Wb[kk][tx * 4];
            acc[0][0] += a0 * b4.x; acc[0][1] += a0 * b4.y; acc[0][2] += a0 * b4.z; acc[0][3] += a0 * b4.w;
            acc[1][0] += a1 * b4.x; acc[1][1] += a1 * b4.y; acc[1][2] += a1 * b4.z; acc[1][3] += a1 * b4.w;
        }
        __syncthreads();
    }
    #pragma unroll
    for (int i = 0; i < 2; i++) {
        int nloc = ty * 2 + i;
        size_t row = row0 + nloc;
        #pragma unroll
        for (int j = 0; j < 4; j++) {
            int c = tx * 4 + j;
            float cv = tanhf(acc[i][j] + b_c[c]);
            size_t uo = ((size_t)b * 128 + c) * NN + n0g + nloc;    // u from x-cols
            float u = bfu2f(XTh[uo]) + bfu2f(XTl[uo]);
            float hv = h[row * HH + c];
            float hn = u * hv + (1.f - u) * cv;
            h[row * HH + c] = hn;
            sT[c][nloc] = hn;
        }
    }
    __syncthreads();
    int c2 = tid >> 2, n8 = (tid & 3) * 8;
    unsigned short h8[8], l8[8];
    #pragma unroll
    for (int j = 0; j < 8; j++) split_bf(sT[c2][n8 + j], h8[j], l8[j]);
    size_t oh = ((size_t)b * 128 + 64 + c2) * NN + n0g + n8;
    *(uint4*)(XTho + oh) = *(uint4*)h8;
    *(uint4*)(XTlo + oh) = *(uint4*)l8;
}

// ---------------- DiffConv operator build ----------------
__global__ void k_deg(const int* __restrict__ ei32, const float* __restrict__ ew,
                      float* __restrict__ degd, float* __restrict__ degs) {
    int e = blockIdx.x * 256 + threadIdx.x;
    float w = ew[e];
    atomicAdd(&degd[ei32[EE + e]], w);
    atomicAdd(&degs[ei32[e]], w);
}
__global__ void k_spadd(const int* __restrict__ ei32, const float* __restrict__ ew,
                        const float* __restrict__ degd, const float* __restrict__ degs,
                        float* __restrict__ temp) {
    int e = blockIdx.x * 256 + threadIdx.x;
    int s = ei32[e], d = ei32[EE + e];
    float w = ew[e];
    float dd = degd[d], ds = degs[s];
    float wfv = dd > 0.f ? w / dd : 0.f;
    float wbv = ds > 0.f ? w / ds : 0.f;
    atomicAdd(&temp[(size_t)d * NN + s], wfv);
    atomicAdd(&temp[(size_t)NN * NN + (size_t)s * NN + d], wbv);
}
__global__ void k_spconv(const float* __restrict__ temp,
                         unsigned short* __restrict__ Mh, unsigned short* __restrict__ Ml) {
    size_t i0 = ((size_t)blockIdx.x * 256 + threadIdx.x) * 8;
    size_t dst = (i0 < (size_t)NN * NN) ? i0 : i0 + (size_t)NN * NN;
    unsigned short h8[8], l8[8];
    #pragma unroll
    for (int j = 0; j < 8; j++) split_bf(temp[i0 + j], h8[j], l8[j]);
    *(uint4*)(Mh + dst) = *(uint4*)h8;
    *(uint4*)(Ml + dst) = *(uint4*)l8;
}

__global__ void k_featd_h(const float* __restrict__ h, float* __restrict__ featd) {
    size_t idx = (size_t)blockIdx.x * 256 + threadIdx.x;
    size_t row = idx >> 6; int c = (int)(idx & 63);
    featd[row * DIN + c] = h[idx];
}

__global__ __launch_bounds__(256) void k_z(
        const float* __restrict__ featd, const float* __restrict__ W_diff,
        const float* __restrict__ b_diff, float* __restrict__ z) {
    int row0 = blockIdx.x * 4;
    __shared__ float sF[4 * DIN];
    int tid = threadIdx.x;
    for (int i = tid; i < 4 * DIN / 4; i += 256)
        *(float4*)&sF[i * 4] = *(const float4*)&featd[(size_t)row0 * DIN + (size_t)i * 4];
    __syncthreads();
    int lr = tid >> 6, ch = tid & 63;
    const float* f = &sF[lr * DIN];
    float acc = b_diff[ch];
    for (int k = 0; k < DIN; k++) acc += f[k] * W_diff[k * HH + ch];
    z[(size_t)(row0 + lr) * HH + ch] = acc;
}

__global__ void k_dec(const float* __restrict__ z, const float* __restrict__ W_dec,
                      const float* __restrict__ b_dec, float* __restrict__ out) {
    size_t idx = (size_t)blockIdx.x * 256 + threadIdx.x;
    size_t row = idx / ODIM; int o = (int)(idx % ODIM);
    const float* zr = z + row * HH;
    float acc = b_dec[o];
    for (int k = 0; k < HH; k++) acc += zr[k] * W_dec[k * ODIM + o];
    int b = (int)(row >> 10), n = (int)(row & 1023);
    int t = o >> 3, f = o & 7;
    out[(((size_t)b * TT + t) * NN + n) * FF + f] = acc;
}

extern "C" void kernel_launch(void* const* d_in, const int* in_sizes, int n_in,
                              void* d_out, int out_size, void* d_ws, size_t ws_size,
                              hipStream_t stream) {
    const float* x      = (const float*)d_in[0];
    const int*   eiraw  = (const int*)  d_in[1];
    const float* ew     = (const float*)d_in[2];
    const float* adj    = (const float*)d_in[3];
    const float* W_enc  = (const float*)d_in[4];
    const float* b_enc  = (const float*)d_in[5];
    const float* emb    = (const float*)d_in[6];
    const float* W_r    = (const float*)d_in[7];
    const float* b_r    = (const float*)d_in[8];
    const float* W_u    = (const float*)d_in[9];
    const float* b_u    = (const float*)d_in[10];
    const float* W_c    = (const float*)d_in[11];
    const float* b_c    = (const float*)d_in[12];
    const float* W_diff = (const float*)d_in[13];
    const float* b_diff = (const float*)d_in[14];
    const float* W_dec  = (const float*)d_in[15];
    const float* b_dec  = (const float*)d_in[16];

    // ---- workspace: 60.0 MiB ----
    unsigned short* Mh  = (unsigned short*)d_ws;          // [4096][1024] hi (8 MiB)
    unsigned short* Ml  = Mh + (size_t)4096 * NN;         // lo (8 MiB)
    unsigned short* XTh = Ml + (size_t)4096 * NN;         // [16][128][1024] hi (4 MiB)
    unsigned short* XTl = XTh + (size_t)BB * 128 * NN;    // lo (4 MiB)
    float* feats = (float*)(XTl + (size_t)BB * 128 * NN); // B*N*512 (32 MiB)
    float* h     = feats + (size_t)BB * NN * FS;          // B*N*64  (4 MiB)
    // overlays
    float* rinv  = feats;                                 // pre-loop only
    float* cinv  = feats + NN;
    float* sptmp = feats + (size_t)5 * 1024 * 1024;       // feats+20MiB (8 MiB)
    int*   eifl  = (int*)(feats + (size_t)7 * 1024 * 1024);
    int*   ei32  = eifl + 4;
    float* degd  = (float*)(ei32 + 2 * EE);
    float* degs  = degd + NN;
    float* featd = feats;                                 // B*N*320 (20 MiB)
    float* z     = h;                                     // h dead after featd

    hipMemsetAsync(h, 0, (size_t)BB * NN * HH * 4, stream);
    hipMemsetAsync(XTh, 0, (size_t)BB * 128 * NN * 2 * 2, stream);  // XTh+XTl (h=0 at t=0)

    // ---- build M = [Af; Af^2; Ab; Ab^2] ----
    k_rowsum<<<NN, 256, 0, stream>>>(adj, rinv);
    k_colsum<<<NN / 256, 256, 0, stream>>>(adj, cinv);
    k_prepA<<<dim3(16, 16), 256, 0, stream>>>(adj, rinv, cinv, Mh, Ml);
    k_msq<<<dim3(16, 16, 2), 256, 0, stream>>>(Mh, Ml);

    for (int t = 0; t < TT; t++) {
        k_encT<<<BB * 64, 128, 0, stream>>>(x, W_enc, b_enc, emb, XTh, XTl, t);
        // 4 operators x [x|h] -> feats cols g*128 + 0..127
        k_hopS2<<<dim3(64, 2, 16), 256, 0, stream>>>(Mh, Ml, XTh, XTl, 0, feats, FS, 128, 0);
        // gates: rh -> XT h-cols, u -> XT x-cols
        k_gates<<<BB * NN / 32, 256, 0, stream>>>(feats, W_r, W_u, b_r, b_u, h, XTh, XTl);
        // 4 operators @ rh -> feats h-cols
        k_hopS2<<<dim3(64, 1, 16), 256, 0, stream>>>(Mh, Ml, XTh, XTl, 64, feats, FS, 128, 64);
        // candidate + h update (writes h f32 + XT h-cols)
        k_cand<<<BB * NN / 32, 256, 0, stream>>>(feats, W_c, b_c, XTh, XTl, h, XTh, XTl);
    }

    // ---- DiffConv readout ----
    k_ei_detect<<<1, 256, 0, stream>>>(eiraw, eifl);
    k_ei_norm<<<2 * EE / 256, 256, 0, stream>>>(eiraw, eifl, ei32);
    hipMemsetAsync(degd, 0, (size_t)2 * NN * 4, stream);
    hipMemsetAsync(sptmp, 0, (size_t)2 * NN * NN * 4, stream);
    k_deg<<<EE / 256, 256, 0, stream>>>(ei32, ew, degd, degs);
    k_spadd<<<EE / 256, 256, 0, stream>>>(ei32, ew, degd, degs, sptmp);
    k_spconv<<<2 * NN * NN / (256 * 8), 256, 0, stream>>>(sptmp, Mh, Ml);  // Sf,Sb -> g0,g2
    k_msq<<<dim3(16, 16, 2), 256, 0, stream>>>(Mh, Ml);                    // squares -> g1,g3
    k_featd_h<<<BB * NN * HH / 256, 256, 0, stream>>>(h, featd);
    // [Sf;Sf2;Sb;Sb2] @ h (hT in XT h-cols) -> featd cols 64 + g*64
    k_hopS2<<<dim3(64, 1, 16), 256, 0, stream>>>(Mh, Ml, XTh, XTl, 64, featd, DIN, 64, 64);
    k_z<<<BB * NN / 4, 256, 0, stream>>>(featd, W_diff, b_diff, z);
    k_dec<<<(BB * NN * ODIM) / 256, 256, 0, stream>>>(z, W_dec, b_dec, (float*)d_out);
}